// Round 3
// baseline (793.473 us; speedup 1.0000x reference)
//
#include <hip/hip_runtime.h>
#include <hip/hip_bf16.h>

typedef unsigned short u16b;                                   // raw bf16 bits
typedef __attribute__((ext_vector_type(8))) short short8;      // 8 bf16 = 4 VGPR (MFMA A/B frag)
typedef __attribute__((ext_vector_type(4))) float floatx4;     // MFMA C/D frag

#define DEV static __device__ __forceinline__

DEV float sh2f(unsigned short s) { union { unsigned u; float f; } c; c.u = ((unsigned)s) << 16; return c.f; }
DEV unsigned short f2b(float f) {
    unsigned u = __float_as_uint(f);
    u += 0x7FFF + ((u >> 16) & 1);      // RNE to bf16
    return (unsigned short)(u >> 16);
}

// ---------------------------------------------------------------------------
// Input dtype sniffer. Reads 4096 u32 words of x. If x is fp32, the LOW half
// of each word is mantissa bits -> as bf16 its exponent is uniform-random ->
// ~25% have exp >= 0xC0 (|v| >= 2^65). Genuine bf16 N(0,1) data: none do.
// flag[0] = 1 -> inputs are fp32;  0 -> inputs are bf16.
// ---------------------------------------------------------------------------
__global__ void detect_k(const unsigned* __restrict__ xw, int* __restrict__ flag) {
    __shared__ int cnt;
    if (threadIdx.x == 0) cnt = 0;
    __syncthreads();
    int my = 0;
    for (int i = threadIdx.x; i < 4096; i += 256) {
        unsigned w = xw[i];
        unsigned e0 = (w >> 7) & 0xFFu;      // low half's bf16 exponent
        if (e0 >= 0xC0u) my++;
    }
    atomicAdd(&cnt, my);
    __syncthreads();
    if (threadIdx.x == 0) flag[0] = (cnt > 64) ? 1 : 0;
}

DEV unsigned short load_cvt(const void* src, size_t idx, int fp32) {
    return fp32 ? f2b(((const float*)src)[idx]) : ((const u16b*)src)[idx];
}

// ---------------------------------------------------------------------------
// Pack + convert the small vectors (gains/biases/qa/ka) into sv (bf16).
// ---------------------------------------------------------------------------
struct VecTab { const void* p[15]; int off[15]; int n[15]; };

__global__ __launch_bounds__(256)
void convert_vecs_k(VecTab tab, const int* __restrict__ flag, u16b* __restrict__ sv) {
    int e = blockIdx.x, fp32 = flag[0];
    const void* s = tab.p[e];
    int n = tab.n[e], off = tab.off[e];
    for (int i = threadIdx.x; i < n; i += 256)
        sv[off + i] = load_cvt(s, i, fp32);
}

// ---------------------------------------------------------------------------
// dtype-converting per-z 2D transpose: src (z, rows, cols) -> dst (z, cols, rows) bf16
// grid: (cols/32, rows/32, z), block (32,8)
// ---------------------------------------------------------------------------
__global__ void transpose_in_k(const void* __restrict__ src, u16b* __restrict__ dst,
                               int rows, int cols, const int* __restrict__ flag) {
    __shared__ u16b tile[32][33];
    int fp32 = flag[0];
    int c0 = blockIdx.x * 32, r0 = blockIdx.y * 32;
    size_t zb = (size_t)blockIdx.z * rows * cols;
    int tx = threadIdx.x, ty = threadIdx.y;
#pragma unroll
    for (int i = 0; i < 32; i += 8)
        tile[ty + i][tx] = load_cvt(src, zb + (size_t)(r0 + ty + i) * cols + c0 + tx, fp32);
    __syncthreads();
#pragma unroll
    for (int i = 0; i < 32; i += 8)
        dst[zb + (size_t)(c0 + ty + i) * rows + r0 + tx] = tile[tx][ty + i];
}

// dtype-converting output transpose: src bf16 (z, rows, cols) -> dst (z, cols, rows)
__global__ void transpose_out_k(const u16b* __restrict__ src, void* __restrict__ dst,
                                int rows, int cols, const int* __restrict__ flag) {
    __shared__ u16b tile[32][33];
    int fp32 = flag[0];
    int c0 = blockIdx.x * 32, r0 = blockIdx.y * 32;
    size_t zb = (size_t)blockIdx.z * rows * cols;
    int tx = threadIdx.x, ty = threadIdx.y;
#pragma unroll
    for (int i = 0; i < 32; i += 8)
        tile[ty + i][tx] = src[zb + (size_t)(r0 + ty + i) * cols + c0 + tx];
    __syncthreads();
#pragma unroll
    for (int i = 0; i < 32; i += 8) {
        size_t idx = zb + (size_t)(c0 + ty + i) * rows + r0 + tx;
        unsigned short v = tile[tx][ty + i];
        if (fp32) ((float*)dst)[idx] = sh2f(v);
        else      ((u16b*)dst)[idx] = v;
    }
}

// ---------------------------------------------------------------------------
// Row LayerNorm over C=256. One wave per row, 4 rows per block.
// Rows r >= valid get padrow copied verbatim (LN of a zero row = ln1_b).
// ---------------------------------------------------------------------------
__global__ __launch_bounds__(256)
void rowln_k(const u16b* __restrict__ src, const u16b* __restrict__ g,
             const u16b* __restrict__ be, const u16b* __restrict__ padrow,
             u16b* __restrict__ dst, int valid, int total) {
    int wv = threadIdx.x >> 6, lane = threadIdx.x & 63;
    int r = blockIdx.x * 4 + wv;
    if (r >= total) return;
    int c = lane * 4;
    if (r >= valid) {
        *(ushort4*)&dst[(size_t)r * 256 + c] = *(const ushort4*)&padrow[c];
        return;
    }
    ushort4 raw = *(const ushort4*)&src[(size_t)r * 256 + c];
    float x0 = sh2f(raw.x), x1 = sh2f(raw.y), x2 = sh2f(raw.z), x3 = sh2f(raw.w);
    float s  = x0 + x1 + x2 + x3;
    float sq = x0 * x0 + x1 * x1 + x2 * x2 + x3 * x3;
#pragma unroll
    for (int o = 32; o; o >>= 1) { s += __shfl_xor(s, o); sq += __shfl_xor(sq, o); }
    float mean = s * (1.f / 256.f);
    float var  = sq * (1.f / 256.f) - mean * mean;
    float rs   = rsqrtf(var + 1e-5f);
    ushort4 o;
    o.x = f2b((x0 - mean) * rs * sh2f(g[c + 0]) + sh2f(be[c + 0]));
    o.y = f2b((x1 - mean) * rs * sh2f(g[c + 1]) + sh2f(be[c + 1]));
    o.z = f2b((x2 - mean) * rs * sh2f(g[c + 2]) + sh2f(be[c + 2]));
    o.w = f2b((x3 - mean) * rs * sh2f(g[c + 3]) + sh2f(be[c + 3]));
    *(ushort4*)&dst[(size_t)r * 256 + c] = o;
}

// ---------------------------------------------------------------------------
// bf16 GEMM: out[M x 256] = A[M x 256] @ W (Wt is N x K = W^T) + epilogue
// 128x128 tile, BK=64, 4 waves of 64x64 (4x4 of 16x16x32 MFMA). grid (M/128, 2)
// EPI: 0 = +bias; 2 = +bias +addm; 3 = gelu(acc+bias). bias/addm nullable.
// ---------------------------------------------------------------------------
template <int EPI>
__global__ __launch_bounds__(256)
void gemm256(const u16b* __restrict__ A, const u16b* __restrict__ Wt,
             const u16b* __restrict__ bias, const u16b* __restrict__ addm,
             u16b* __restrict__ out) {
    __shared__ u16b As[128 * 72];
    __shared__ u16b Bs[128 * 72];
    const int tid = threadIdx.x;
    const int m0 = blockIdx.x * 128, n0 = blockIdx.y * 128;
    const int wv = tid >> 6, lane = tid & 63;
    const int wrow = (wv >> 1) * 64, wcol = (wv & 1) * 64;
    const int fr = lane & 15;            // frag row (m for A, n for B), also C col
    const int fq = lane >> 4;            // quad: k offset fq*8; C row offset fq*4
    floatx4 acc[4][4];
    const floatx4 zero = {0.f, 0.f, 0.f, 0.f};
#pragma unroll
    for (int i = 0; i < 4; ++i)
#pragma unroll
        for (int j = 0; j < 4; ++j) acc[i][j] = zero;

    for (int kt = 0; kt < 256; kt += 64) {
#pragma unroll
        for (int kk = 0; kk < 4; ++kk) {
            int chunk = tid + kk * 256;              // 1024 chunks of 8 elems
            int row = chunk >> 3, col = (chunk & 7) * 8;
            *(uint4*)&As[row * 72 + col] = *(const uint4*)&A[(size_t)(m0 + row) * 256 + kt + col];
            *(uint4*)&Bs[row * 72 + col] = *(const uint4*)&Wt[(size_t)(n0 + row) * 256 + kt + col];
        }
        __syncthreads();
#pragma unroll
        for (int s = 0; s < 2; ++s) {
            short8 af[4], bfr[4];
#pragma unroll
            for (int i = 0; i < 4; ++i)
                af[i] = *(short8*)&As[(wrow + i * 16 + fr) * 72 + s * 32 + fq * 8];
#pragma unroll
            for (int j = 0; j < 4; ++j)
                bfr[j] = *(short8*)&Bs[(wcol + j * 16 + fr) * 72 + s * 32 + fq * 8];
#pragma unroll
            for (int i = 0; i < 4; ++i)
#pragma unroll
                for (int j = 0; j < 4; ++j)
                    acc[i][j] = __builtin_amdgcn_mfma_f32_16x16x32_bf16(af[i], bfr[j], acc[i][j], 0, 0, 0);
        }
        __syncthreads();
    }
    // epilogue; C/D layout: col = lane&15, row = (lane>>4)*4 + reg
    float bv[4];
#pragma unroll
    for (int j = 0; j < 4; ++j) bv[j] = bias ? sh2f(bias[n0 + wcol + j * 16 + fr]) : 0.f;
#pragma unroll
    for (int i = 0; i < 4; ++i) {
#pragma unroll
        for (int r = 0; r < 4; ++r) {
            int row = m0 + wrow + i * 16 + fq * 4 + r;
            size_t ro = (size_t)row * 256;
#pragma unroll
            for (int j = 0; j < 4; ++j) {
                int col = n0 + wcol + j * 16 + fr;
                float val = acc[i][j][r] + bv[j];
                if (EPI == 2) val += sh2f(addm[ro + col]);
                if (EPI == 3) val = 0.5f * val * (1.0f + erff(val * 0.70710678118654752f));
                out[ro + col] = f2b(val);
            }
        }
    }
}

// ---------------------------------------------------------------------------
// Softmax pooling over the 125 gathered window rows of one b=(n,t).
//   logits[l,h] = scale * (sum_c S[row(l),c]*mult[c]*aw[c,h] + ab[h])
//   w = softmax over l;  outp[b, h*32+d] = sum_l w[l,h] * S[row(l), h*32+d]
// S has 51200 valid rows + pad row at 51200. mult==nullptr -> ones.
// ---------------------------------------------------------------------------
__global__ __launch_bounds__(256)
void pool_k(const u16b* __restrict__ S, const float* __restrict__ mult,
            const u16b* __restrict__ aw, const u16b* __restrict__ ab,
            float* __restrict__ outp) {
    __shared__ float slog[125 * 8];
    __shared__ float saw[2048];
    __shared__ float smult[256];
    __shared__ float sab[8];
    int b = blockIdx.x, tid = threadIdx.x;
    int n = b >> 6, t = b & 63;
    int lane = tid & 63, wv = tid >> 6;
    for (int i = tid; i < 2048; i += 256) saw[i] = sh2f(aw[i]);
    smult[tid] = mult ? mult[(size_t)b * 256 + tid] : 1.0f;
    if (tid < 8) sab[tid] = sh2f(ab[tid]);
    __syncthreads();
    // phase 1: logits. lane = g*8 + h  (g = channel-group of 32, h = head)
    int g = lane >> 3, h = lane & 7;
    for (int l = wv; l < 125; l += 4) {
        int w = l / 25, v = l - w * 25;
        int tt = t + w - 2;
        size_t row = ((unsigned)tt < 64u) ? (size_t)(n * 64 + tt) * 25 + v : 51200u;
        const u16b* Sr = S + row * 256;
        float p = 0.f;
#pragma unroll
        for (int c8 = 0; c8 < 4; ++c8) {
            int c = g * 32 + c8 * 8;
            short8 v8 = *(const short8*)&Sr[c];
#pragma unroll
            for (int u = 0; u < 8; ++u)
                p += sh2f((unsigned short)v8[u]) * smult[c + u] * saw[(c + u) * 8 + h];
        }
        p += __shfl_xor(p, 8); p += __shfl_xor(p, 16); p += __shfl_xor(p, 32);
        if (g == 0) slog[l * 8 + h] = (p + sab[h]) * 0.17677669529663687f;   // 1/sqrt(32)
    }
    __syncthreads();
    // phase 2: softmax over l per head (wave wv handles heads wv, wv+4)
    for (int hh = wv; hh < 8; hh += 4) {
        float v0 = (lane < 125) ? slog[lane * 8 + hh] : -1e30f;
        float v1 = (lane + 64 < 125) ? slog[(lane + 64) * 8 + hh] : -1e30f;
        float mx = fmaxf(v0, v1);
#pragma unroll
        for (int o = 32; o; o >>= 1) mx = fmaxf(mx, __shfl_xor(mx, o));
        float e0 = (lane < 125) ? __expf(v0 - mx) : 0.f;
        float e1 = (lane + 64 < 125) ? __expf(v1 - mx) : 0.f;
        float s = e0 + e1;
#pragma unroll
        for (int o = 32; o; o >>= 1) s += __shfl_xor(s, o);
        float inv = 1.f / s;
        if (lane < 125) slog[lane * 8 + hh] = e0 * inv;
        if (lane + 64 < 125) slog[(lane + 64) * 8 + hh] = e1 * inv;
    }
    __syncthreads();
    // phase 3: pooled value from RAW rows (L2-hot rereads)
    int h2 = tid >> 5, d = tid & 31;
    float acc = 0.f;
    for (int l = 0; l < 125; ++l) {
        int w = l / 25, v = l - w * 25;
        int tt = t + w - 2;
        size_t row = ((unsigned)tt < 64u) ? (size_t)(n * 64 + tt) * 25 + v : 51200u;
        acc += slog[l * 8 + h2] * sh2f(S[row * 256 + h2 * 32 + d]);
    }
    outp[(size_t)b * 256 + tid] = acc;
}

// ---------------------------------------------------------------------------
// Window mean: qbar[b,v,:] = mean_w q_full[row(w,v)]; vbarP = mean_w v_full * pk[b]
// one block per b; wave wv handles v = wv, wv+4, ...
// ---------------------------------------------------------------------------
__global__ __launch_bounds__(256)
void winmean_k(const u16b* __restrict__ qf, const u16b* __restrict__ vf,
               const float* __restrict__ pk, u16b* __restrict__ qbar,
               u16b* __restrict__ vbarP) {
    int b = blockIdx.x, tid = threadIdx.x;
    int n = b >> 6, t = b & 63;
    int wv = tid >> 6, lane = tid & 63;
    int c = lane * 4;
    float4 pkv = *(const float4*)&pk[(size_t)b * 256 + c];
    for (int v = wv; v < 25; v += 4) {
        float q0 = 0, q1 = 0, q2 = 0, q3 = 0, s0 = 0, s1 = 0, s2 = 0, s3 = 0;
#pragma unroll
        for (int w = 0; w < 5; ++w) {
            int tt = t + w - 2;
            size_t row = ((unsigned)tt < 64u) ? (size_t)(n * 64 + tt) * 25 + v : 51200u;
            ushort4 qr = *(const ushort4*)&qf[row * 256 + c];
            ushort4 vr = *(const ushort4*)&vf[row * 256 + c];
            q0 += sh2f(qr.x); q1 += sh2f(qr.y); q2 += sh2f(qr.z); q3 += sh2f(qr.w);
            s0 += sh2f(vr.x); s1 += sh2f(vr.y); s2 += sh2f(vr.z); s3 += sh2f(vr.w);
        }
        size_t ro = ((size_t)b * 25 + v) * 256 + c;
        ushort4 oq, ov;
        oq.x = f2b(q0 * 0.2f); oq.y = f2b(q1 * 0.2f); oq.z = f2b(q2 * 0.2f); oq.w = f2b(q3 * 0.2f);
        ov.x = f2b(s0 * 0.2f * pkv.x); ov.y = f2b(s1 * 0.2f * pkv.y);
        ov.z = f2b(s2 * 0.2f * pkv.z); ov.w = f2b(s3 * 0.2f * pkv.w);
        *(ushort4*)&qbar[ro] = oq;
        *(ushort4*)&vbarP[ro] = ov;
    }
}

// ---------------------------------------------------------------------------
extern "C" void kernel_launch(void* const* d_in, const int* in_sizes, int n_in,
                              void* d_out, int out_size, void* d_ws, size_t ws_size,
                              hipStream_t stream) {
    (void)in_sizes; (void)n_in; (void)out_size; (void)ws_size;
    const void* x    = d_in[0];
    const void* ln1g = d_in[1];  const void* ln1b = d_in[2];
    const void* q_w  = d_in[3];  const void* q_b  = d_in[4];
    const void* qa_w = d_in[5];  const void* qa_b = d_in[6];
    const void* k_w  = d_in[7];  const void* k_b  = d_in[8];
    const void* ka_w = d_in[9];  const void* ka_b = d_in[10];
    const void* v_w  = d_in[11]; const void* v_b  = d_in[12];
    const void* t_w  = d_in[13]; const void* t_b  = d_in[14];
    const void* p_w  = d_in[15]; const void* p_b  = d_in[16];
    const void* ffng = d_in[17]; const void* ffnb = d_in[18];
    const void* w1   = d_in[19]; const void* b1   = d_in[20];
    const void* w2   = d_in[21]; const void* b2   = d_in[22];

    char* ws = (char*)d_ws;
    size_t off = 0;
    auto alloc = [&](size_t bytes) { void* p = ws + off; off += (bytes + 255) & ~(size_t)255; return p; };
    const size_t RPAD = 51328;           // 51200 valid rows + 128 pad rows
    int*   flag = (int*)alloc(256);
    u16b*  sv  = (u16b*)alloc(8192 * 2);                // packed small vectors
    u16b*  wT  = (u16b*)alloc((size_t)7 * 65536 * 2);   // qT kT vT pT tT w1T w2T
    u16b*  xT  = (u16b*)alloc((size_t)51200 * 256 * 2);
    u16b*  B1  = (u16b*)alloc(RPAD * 256 * 2);          // ln_x -> qbar -> h1
    u16b*  B2  = (u16b*)alloc(RPAD * 256 * 2);          // q_full -> tmp -> (h1 src) fn2
    u16b*  B3  = (u16b*)alloc(RPAD * 256 * 2);          // k_full -> vbarP
    u16b*  B4  = (u16b*)alloc(RPAD * 256 * 2);          // v_full -> fn
    u16b*  att = (u16b*)alloc((size_t)51200 * 256 * 2); // att, then y in place
    float* pq  = (float*)alloc((size_t)2048 * 256 * 4);
    float* pk  = (float*)alloc((size_t)2048 * 256 * 4);

    u16b* qT  = wT + 0 * 65536; u16b* kT  = wT + 1 * 65536;
    u16b* vT  = wT + 2 * 65536; u16b* pT  = wT + 3 * 65536;
    u16b* tT  = wT + 4 * 65536; u16b* w1T = wT + 5 * 65536;
    u16b* w2T = wT + 6 * 65536;

    // packed small-vector offsets (elements)
    const int O_LN1G = 0, O_LN1B = 256, O_QB = 512, O_KB = 768, O_VB = 1024,
              O_TB = 1280, O_PB = 1536, O_FFNG = 1792, O_FFNB = 2048,
              O_B1 = 2304, O_B2 = 2560, O_QAB = 2816, O_KAB = 2824,
              O_QAW = 2832, O_KAW = 4880;

    // 0) dtype detection
    detect_k<<<1, 256, 0, stream>>>((const unsigned*)x, flag);
    // 1) small-vector conversion
    VecTab tab;
    const void* vp[15] = {ln1g, ln1b, q_b, k_b, v_b, t_b, p_b, ffng, ffnb, b1, b2, qa_b, ka_b, qa_w, ka_w};
    const int vo[15] = {O_LN1G, O_LN1B, O_QB, O_KB, O_VB, O_TB, O_PB, O_FFNG, O_FFNB, O_B1, O_B2, O_QAB, O_KAB, O_QAW, O_KAW};
    const int vn[15] = {256, 256, 256, 256, 256, 256, 256, 256, 256, 256, 256, 8, 8, 2048, 2048};
    for (int i = 0; i < 15; ++i) { tab.p[i] = vp[i]; tab.off[i] = vo[i]; tab.n[i] = vn[i]; }
    convert_vecs_k<<<15, 256, 0, stream>>>(tab, flag, sv);

    dim3 tb(32, 8);
    // 2) weight transposes (K x N -> N x K), converting dtype
    const void* wsrc[7] = {q_w, k_w, v_w, p_w, t_w, w1, w2};
    u16b* wdst[7] = {qT, kT, vT, pT, tT, w1T, w2T};
    for (int i = 0; i < 7; ++i)
        transpose_in_k<<<dim3(8, 8, 1), tb, 0, stream>>>(wsrc[i], wdst[i], 256, 256, flag);
    // 3) x (n, 256, 1600) -> xT (n, 1600, 256), converting dtype
    transpose_in_k<<<dim3(50, 8, 32), tb, 0, stream>>>(x, xT, 256, 1600, flag);
    // 4) ln_x (51328 rows; pad rows = ln1_b)
    rowln_k<<<12832, 256, 0, stream>>>(xT, sv + O_LN1G, sv + O_LN1B, sv + O_LN1B, B1, 51200, 51328);
    // 5-7) q_full / k_full / v_full
    gemm256<0><<<dim3(401, 2), 256, 0, stream>>>(B1, qT, sv + O_QB, nullptr, B2);
    gemm256<0><<<dim3(401, 2), 256, 0, stream>>>(B1, kT, sv + O_KB, nullptr, B3);
    gemm256<0><<<dim3(401, 2), 256, 0, stream>>>(B1, vT, sv + O_VB, nullptr, B4);
    // 8) pooled q -> pq;  9) pooled k (logits scaled by pq) -> pk
    pool_k<<<2048, 256, 0, stream>>>(B2, nullptr, sv + O_QAW, sv + O_QAB, pq);
    pool_k<<<2048, 256, 0, stream>>>(B3, pq, sv + O_KAW, sv + O_KAB, pk);
    // 10) window means: qbar (into B1), vbarP (into B3)
    winmean_k<<<2048, 256, 0, stream>>>(B2, B4, pk, B1, B3);
    // 11) att = qbar @ p_w + p_b + x_residual
    gemm256<2><<<dim3(400, 2), 256, 0, stream>>>(B1, pT, sv + O_PB, xT, att);
    // 12) tmp = vbarP @ t_w + t_b   (into B2)
    gemm256<0><<<dim3(400, 2), 256, 0, stream>>>(B3, tT, sv + O_TB, nullptr, B2);
    // 13) att += tmp @ p_w          (in place)
    gemm256<2><<<dim3(400, 2), 256, 0, stream>>>(B2, pT, nullptr, att, att);
    // 14) fn = LN(att) with ffn params (into B4)
    rowln_k<<<12800, 256, 0, stream>>>(att, sv + O_FFNG, sv + O_FFNB, nullptr, B4, 51200, 51200);
    // 15) h1 = gelu(fn @ w1 + b1) (into B1)
    gemm256<3><<<dim3(400, 2), 256, 0, stream>>>(B4, w1T, sv + O_B1, nullptr, B1);
    // 16) y = h1 @ w2 + b2 + att (in place into att)
    gemm256<2><<<dim3(400, 2), 256, 0, stream>>>(B1, w2T, sv + O_B2, att, att);
    // 17) y (n, 1600, 256) -> out (n, 256, 1600), converting dtype
    transpose_out_k<<<dim3(8, 50, 32), tb, 0, stream>>>(att, d_out, 1600, 256, flag);
}

// Round 4
// 576.911 us; speedup vs baseline: 1.3754x; 1.3754x over previous
//
#include <hip/hip_runtime.h>
#include <hip/hip_bf16.h>

typedef unsigned short u16b;                                   // raw bf16 bits
typedef __attribute__((ext_vector_type(8))) short short8;      // 8 bf16 = 4 VGPR (MFMA A/B frag)
typedef __attribute__((ext_vector_type(4))) float floatx4;     // MFMA C/D frag

#define DEV static __device__ __forceinline__

DEV float sh2f(unsigned short s) { union { unsigned u; float f; } c; c.u = ((unsigned)s) << 16; return c.f; }
DEV unsigned short f2b(float f) {
    unsigned u = __float_as_uint(f);
    u += 0x7FFF + ((u >> 16) & 1);      // RNE to bf16
    return (unsigned short)(u >> 16);
}

// packed small-vector offsets (elements) — shared host/device
constexpr int O_LN1G = 0, O_LN1B = 256, O_QB = 512, O_KB = 768, O_VB = 1024,
              O_TB = 1280, O_PB = 1536, O_FFNG = 1792, O_FFNB = 2048,
              O_B1 = 2304, O_B2 = 2560, O_QAB = 2816, O_KAB = 2824,
              O_QAW = 2832, O_KAW = 4880;

// ---------------------------------------------------------------------------
// Input dtype sniffer. flag[0] = 1 -> inputs are fp32;  0 -> bf16.
// ---------------------------------------------------------------------------
__global__ void detect_k(const unsigned* __restrict__ xw, int* __restrict__ flag) {
    __shared__ int cnt;
    if (threadIdx.x == 0) cnt = 0;
    __syncthreads();
    int my = 0;
    for (int i = threadIdx.x; i < 4096; i += 256) {
        unsigned w = xw[i];
        unsigned e0 = (w >> 7) & 0xFFu;      // low half's bf16 exponent
        if (e0 >= 0xC0u) my++;
    }
    atomicAdd(&cnt, my);
    __syncthreads();
    if (threadIdx.x == 0) flag[0] = (cnt > 64) ? 1 : 0;
}

DEV unsigned short load_cvt(const void* src, size_t idx, int fp32) {
    return fp32 ? f2b(((const float*)src)[idx]) : ((const u16b*)src)[idx];
}

// ---------------------------------------------------------------------------
// Pack + convert the small vectors (gains/biases/qa/ka) into sv (bf16).
// ---------------------------------------------------------------------------
struct VecTab { const void* p[15]; int off[15]; int n[15]; };

__global__ __launch_bounds__(256)
void convert_vecs_k(VecTab tab, const int* __restrict__ flag, u16b* __restrict__ sv) {
    int e = blockIdx.x, fp32 = flag[0];
    const void* s = tab.p[e];
    int n = tab.n[e], off = tab.off[e];
    for (int i = threadIdx.x; i < n; i += 256)
        sv[off + i] = load_cvt(s, i, fp32);
}

// ---------------------------------------------------------------------------
// dtype-converting per-z 2D transpose: src (z, rows, cols) -> dst (z, cols, rows) bf16
// ---------------------------------------------------------------------------
__global__ void transpose_in_k(const void* __restrict__ src, u16b* __restrict__ dst,
                               int rows, int cols, const int* __restrict__ flag) {
    __shared__ u16b tile[32][33];
    int fp32 = flag[0];
    int c0 = blockIdx.x * 32, r0 = blockIdx.y * 32;
    size_t zb = (size_t)blockIdx.z * rows * cols;
    int tx = threadIdx.x, ty = threadIdx.y;
#pragma unroll
    for (int i = 0; i < 32; i += 8)
        tile[ty + i][tx] = load_cvt(src, zb + (size_t)(r0 + ty + i) * cols + c0 + tx, fp32);
    __syncthreads();
#pragma unroll
    for (int i = 0; i < 32; i += 8)
        dst[zb + (size_t)(c0 + ty + i) * rows + r0 + tx] = tile[tx][ty + i];
}

__global__ void transpose_out_k(const u16b* __restrict__ src, void* __restrict__ dst,
                                int rows, int cols, const int* __restrict__ flag) {
    __shared__ u16b tile[32][33];
    int fp32 = flag[0];
    int c0 = blockIdx.x * 32, r0 = blockIdx.y * 32;
    size_t zb = (size_t)blockIdx.z * rows * cols;
    int tx = threadIdx.x, ty = threadIdx.y;
#pragma unroll
    for (int i = 0; i < 32; i += 8)
        tile[ty + i][tx] = src[zb + (size_t)(r0 + ty + i) * cols + c0 + tx];
    __syncthreads();
#pragma unroll
    for (int i = 0; i < 32; i += 8) {
        size_t idx = zb + (size_t)(c0 + ty + i) * rows + r0 + tx;
        unsigned short v = tile[tx][ty + i];
        if (fp32) ((float*)dst)[idx] = sh2f(v);
        else      ((u16b*)dst)[idx] = v;
    }
}

// ---------------------------------------------------------------------------
// Row LayerNorm over C=256. One wave per row, 4 rows per block.
// Rows r >= valid get padrow copied verbatim (LN of a zero row = ln1_b).
// ---------------------------------------------------------------------------
__global__ __launch_bounds__(256)
void rowln_k(const u16b* __restrict__ src, const u16b* __restrict__ g,
             const u16b* __restrict__ be, const u16b* __restrict__ padrow,
             u16b* __restrict__ dst, int valid, int total) {
    int wv = threadIdx.x >> 6, lane = threadIdx.x & 63;
    int r = blockIdx.x * 4 + wv;
    if (r >= total) return;
    int c = lane * 4;
    if (r >= valid) {
        *(ushort4*)&dst[(size_t)r * 256 + c] = *(const ushort4*)&padrow[c];
        return;
    }
    ushort4 raw = *(const ushort4*)&src[(size_t)r * 256 + c];
    float x0 = sh2f(raw.x), x1 = sh2f(raw.y), x2 = sh2f(raw.z), x3 = sh2f(raw.w);
    float s  = x0 + x1 + x2 + x3;
    float sq = x0 * x0 + x1 * x1 + x2 * x2 + x3 * x3;
#pragma unroll
    for (int o = 32; o; o >>= 1) { s += __shfl_xor(s, o); sq += __shfl_xor(sq, o); }
    float mean = s * (1.f / 256.f);
    float var  = sq * (1.f / 256.f) - mean * mean;
    float rs   = rsqrtf(var + 1e-5f);
    ushort4 o;
    o.x = f2b((x0 - mean) * rs * sh2f(g[c + 0]) + sh2f(be[c + 0]));
    o.y = f2b((x1 - mean) * rs * sh2f(g[c + 1]) + sh2f(be[c + 1]));
    o.z = f2b((x2 - mean) * rs * sh2f(g[c + 2]) + sh2f(be[c + 2]));
    o.w = f2b((x3 - mean) * rs * sh2f(g[c + 3]) + sh2f(be[c + 3]));
    *(ushort4*)&dst[(size_t)r * 256 + c] = o;
}

// ---------------------------------------------------------------------------
// bf16 GEMM: out[M x 256] = A[M x 256] @ W (Wt is N x K = W^T) + epilogue
// EPI: 0 = +bias; 2 = +bias +addm; 3 = gelu(acc+bias). bias/addm nullable.
// ---------------------------------------------------------------------------
template <int EPI>
__global__ __launch_bounds__(256)
void gemm256(const u16b* __restrict__ A, const u16b* __restrict__ Wt,
             const u16b* __restrict__ bias, const u16b* __restrict__ addm,
             u16b* __restrict__ out) {
    __shared__ u16b As[128 * 72];
    __shared__ u16b Bs[128 * 72];
    const int tid = threadIdx.x;
    const int m0 = blockIdx.x * 128, n0 = blockIdx.y * 128;
    const int wv = tid >> 6, lane = tid & 63;
    const int wrow = (wv >> 1) * 64, wcol = (wv & 1) * 64;
    const int fr = lane & 15;            // frag row (m for A, n for B), also C col
    const int fq = lane >> 4;            // quad: k offset fq*8; C row offset fq*4
    floatx4 acc[4][4];
    const floatx4 zero = {0.f, 0.f, 0.f, 0.f};
#pragma unroll
    for (int i = 0; i < 4; ++i)
#pragma unroll
        for (int j = 0; j < 4; ++j) acc[i][j] = zero;

    for (int kt = 0; kt < 256; kt += 64) {
#pragma unroll
        for (int kk = 0; kk < 4; ++kk) {
            int chunk = tid + kk * 256;              // 1024 chunks of 8 elems
            int row = chunk >> 3, col = (chunk & 7) * 8;
            *(uint4*)&As[row * 72 + col] = *(const uint4*)&A[(size_t)(m0 + row) * 256 + kt + col];
            *(uint4*)&Bs[row * 72 + col] = *(const uint4*)&Wt[(size_t)(n0 + row) * 256 + kt + col];
        }
        __syncthreads();
#pragma unroll
        for (int s = 0; s < 2; ++s) {
            short8 af[4], bfr[4];
#pragma unroll
            for (int i = 0; i < 4; ++i)
                af[i] = *(short8*)&As[(wrow + i * 16 + fr) * 72 + s * 32 + fq * 8];
#pragma unroll
            for (int j = 0; j < 4; ++j)
                bfr[j] = *(short8*)&Bs[(wcol + j * 16 + fr) * 72 + s * 32 + fq * 8];
#pragma unroll
            for (int i = 0; i < 4; ++i)
#pragma unroll
                for (int j = 0; j < 4; ++j)
                    acc[i][j] = __builtin_amdgcn_mfma_f32_16x16x32_bf16(af[i], bfr[j], acc[i][j], 0, 0, 0);
        }
        __syncthreads();
    }
    // epilogue; C/D layout: col = lane&15, row = (lane>>4)*4 + reg
    float bv[4];
#pragma unroll
    for (int j = 0; j < 4; ++j) bv[j] = bias ? sh2f(bias[n0 + wcol + j * 16 + fr]) : 0.f;
#pragma unroll
    for (int i = 0; i < 4; ++i) {
#pragma unroll
        for (int r = 0; r < 4; ++r) {
            int row = m0 + wrow + i * 16 + fq * 4 + r;
            size_t ro = (size_t)row * 256;
#pragma unroll
            for (int j = 0; j < 4; ++j) {
                int col = n0 + wcol + j * 16 + fr;
                float val = acc[i][j][r] + bv[j];
                if (EPI == 2) val += sh2f(addm[ro + col]);
                if (EPI == 3) val = 0.5f * val * (1.0f + erff(val * 0.70710678118654752f));
                out[ro + col] = f2b(val);
            }
        }
    }
}

// ---------------------------------------------------------------------------
// One softmax-pool stage (q or k) for block b:
//   logits[l,h] = scale * (sum_c S[row(l),c] * (mult[c]) * aw[c,h] + ab[h])
//   w = softmax_l; outPool[h*32+d] = sum_l w[l,h] * S[row(l), h*32+d]
// Logits via one 16x16x32 MFMA n-tile (16 cols, 8 valid heads), A-frags
// loaded 16B straight from global (quads of one row cover a 64B line).
// 512 threads = 8 waves; wave wv owns m-tile wv (rows wv*16..wv*16+15).
// ---------------------------------------------------------------------------
DEV void pool_stage(const u16b* __restrict__ S, const u16b* __restrict__ sv,
                    int awoff, int aboff, const float* mult, float* outPool,
                    const int* srow, u16b* su, float* slog, float* spool, int tid) {
    // build su rows 0..7 : su[h*260 + c] = aw[c,h] (* mult[c]); rows 8..15 stay 0
    for (int i = tid; i < 2048; i += 512) {
        int c = i >> 3, h = i & 7;
        float w = sh2f(sv[awoff + i]);
        if (mult) w *= mult[c];
        su[h * 260 + c] = f2b(w);
    }
    __syncthreads();
    int wv = tid >> 6, lane = tid & 63;
    int fr = lane & 15, fq = lane >> 4;
    floatx4 acc = {0.f, 0.f, 0.f, 0.f};
    const u16b* Ar = S + (size_t)srow[wv * 16 + fr] * 256;
#pragma unroll
    for (int s = 0; s < 8; ++s) {
        short8 a  = *(const short8*)&Ar[s * 32 + fq * 8];
        short8 bb = *(const short8*)&su[fr * 260 + s * 32 + fq * 8];
        acc = __builtin_amdgcn_mfma_f32_16x16x32_bf16(a, bb, acc, 0, 0, 0);
    }
    float abv = sh2f(sv[aboff + (fr & 7)]);
    if (fr < 8) {
#pragma unroll
        for (int r = 0; r < 4; ++r)
            slog[(wv * 16 + fq * 4 + r) * 9 + fr] = (acc[r] + abv) * 0.17677669529663687f;
    }
    __syncthreads();
    // softmax over l=0..124 for head h = wv (8 waves, 8 heads)
    {
        int h = wv;
        float v0 = (lane < 125) ? slog[lane * 9 + h] : -1e30f;
        float v1 = (lane + 64 < 125) ? slog[(lane + 64) * 9 + h] : -1e30f;
        float mx = fmaxf(v0, v1);
#pragma unroll
        for (int o = 32; o; o >>= 1) mx = fmaxf(mx, __shfl_xor(mx, o));
        float e0 = (lane < 125) ? __expf(v0 - mx) : 0.f;
        float e1 = (lane + 64 < 125) ? __expf(v1 - mx) : 0.f;
        float s = e0 + e1;
#pragma unroll
        for (int o = 32; o; o >>= 1) s += __shfl_xor(s, o);
        float inv = 1.f / s;
        if (lane < 125) slog[lane * 9 + h] = e0 * inv;
        if (lane + 64 < 125) slog[(lane + 64) * 9 + h] = e1 * inv;
    }
    __syncthreads();
    // pooled value from raw rows (L2-hot); thread = (half of l-range, channel)
    int c = tid & 255, half = tid >> 8;
    int h2 = c >> 5;
    float accp = 0.f;
    int l0 = half ? 63 : 0, l1 = half ? 125 : 63;
    for (int l = l0; l < l1; ++l)
        accp += slog[l * 9 + h2] * sh2f(S[(size_t)srow[l] * 256 + c]);
    spool[half * 256 + c] = accp;
    __syncthreads();
    if (tid < 256) outPool[tid] = spool[tid] + spool[256 + tid];
    __syncthreads();
}

// ---------------------------------------------------------------------------
// Fused q-pool, k-pool, window-means. One block per b=(n,t), 512 threads.
// XCD swizzle: consecutive-t blocks land on the same XCD for L2 gather reuse.
// Writes qbar (mean_w q) and vbarP (mean_w v * pk) as (b,v) rows.
// ---------------------------------------------------------------------------
__global__ __launch_bounds__(512)
void pool_fused(const u16b* __restrict__ qf, const u16b* __restrict__ kf,
                const u16b* __restrict__ vf, const u16b* __restrict__ sv,
                u16b* __restrict__ qbar, u16b* __restrict__ vbarP) {
    __shared__ int srow[128];
    __shared__ u16b su[16 * 260];
    __shared__ float slog[128 * 9];
    __shared__ float spool[512];
    __shared__ float spq[256], spk[256];
    int bid = blockIdx.x;
    int b = ((bid & 7) << 8) | (bid >> 3);   // XCD-aware: bid%8 -> n-group
    int n = b >> 6, t = b & 63;
    int tid = threadIdx.x;
    if (tid < 128) {
        int l = tid < 125 ? tid : 124;       // clamp; rows >=125 never used downstream
        int w = l / 25, v = l - w * 25, tt = t + w - 2;
        srow[tid] = ((unsigned)tt < 64u) ? (n * 64 + tt) * 25 + v : 51200;
    }
    for (int i = tid; i < 8 * 260; i += 512) su[8 * 260 + i] = 0;
    __syncthreads();
    // q-pool -> spq (stays in LDS)
    pool_stage(qf, sv, O_QAW, O_QAB, nullptr, spq, srow, su, slog, spool, tid);
    // qbar = mean_w q
    for (int i = tid; i < 6400; i += 512) {
        int v = i >> 8, c = i & 255;
        float s = 0.f;
#pragma unroll
        for (int w = 0; w < 5; ++w) s += sh2f(qf[(size_t)srow[w * 25 + v] * 256 + c]);
        qbar[((size_t)b * 25 + v) * 256 + c] = f2b(s * 0.2f);
    }
    // k-pool with pq modulation -> spk
    pool_stage(kf, sv, O_KAW, O_KAB, spq, spk, srow, su, slog, spool, tid);
    // vbarP = mean_w v * pk
    for (int i = tid; i < 6400; i += 512) {
        int v = i >> 8, c = i & 255;
        float s = 0.f;
#pragma unroll
        for (int w = 0; w < 5; ++w) s += sh2f(vf[(size_t)srow[w * 25 + v] * 256 + c]);
        vbarP[((size_t)b * 25 + v) * 256 + c] = f2b(s * 0.2f * spk[c]);
    }
}

// ---------------------------------------------------------------------------
extern "C" void kernel_launch(void* const* d_in, const int* in_sizes, int n_in,
                              void* d_out, int out_size, void* d_ws, size_t ws_size,
                              hipStream_t stream) {
    (void)in_sizes; (void)n_in; (void)out_size; (void)ws_size;
    const void* x    = d_in[0];
    const void* ln1g = d_in[1];  const void* ln1b = d_in[2];
    const void* q_w  = d_in[3];  const void* q_b  = d_in[4];
    const void* qa_w = d_in[5];  const void* qa_b = d_in[6];
    const void* k_w  = d_in[7];  const void* k_b  = d_in[8];
    const void* ka_w = d_in[9];  const void* ka_b = d_in[10];
    const void* v_w  = d_in[11]; const void* v_b  = d_in[12];
    const void* t_w  = d_in[13]; const void* t_b  = d_in[14];
    const void* p_w  = d_in[15]; const void* p_b  = d_in[16];
    const void* ffng = d_in[17]; const void* ffnb = d_in[18];
    const void* w1   = d_in[19]; const void* b1   = d_in[20];
    const void* w2   = d_in[21]; const void* b2   = d_in[22];

    char* ws = (char*)d_ws;
    size_t off = 0;
    auto alloc = [&](size_t bytes) { void* p = ws + off; off += (bytes + 255) & ~(size_t)255; return p; };
    const size_t RPAD = 51328;           // 51200 valid rows + 128 pad rows
    int*   flag = (int*)alloc(256);
    u16b*  sv  = (u16b*)alloc(8192 * 2);                // packed small vectors
    u16b*  wT  = (u16b*)alloc((size_t)7 * 65536 * 2);   // qT kT vT pT tT w1T w2T
    u16b*  xT  = (u16b*)alloc((size_t)51200 * 256 * 2);
    u16b*  B1  = (u16b*)alloc(RPAD * 256 * 2);          // ln_x -> qbar -> h1
    u16b*  B2  = (u16b*)alloc(RPAD * 256 * 2);          // q_full -> tmp
    u16b*  B3  = (u16b*)alloc(RPAD * 256 * 2);          // k_full
    u16b*  B4  = (u16b*)alloc(RPAD * 256 * 2);          // v_full -> fn
    u16b*  att = (u16b*)alloc((size_t)51200 * 256 * 2); // att, then y in place
    u16b*  vbb = (u16b*)alloc((size_t)51200 * 256 * 2); // vbarP

    u16b* qT  = wT + 0 * 65536; u16b* kT  = wT + 1 * 65536;
    u16b* vT  = wT + 2 * 65536; u16b* pT  = wT + 3 * 65536;
    u16b* tT  = wT + 4 * 65536; u16b* w1T = wT + 5 * 65536;
    u16b* w2T = wT + 6 * 65536;

    // 0) dtype detection
    detect_k<<<1, 256, 0, stream>>>((const unsigned*)x, flag);
    // 1) small-vector conversion
    VecTab tab;
    const void* vp[15] = {ln1g, ln1b, q_b, k_b, v_b, t_b, p_b, ffng, ffnb, b1, b2, qa_b, ka_b, qa_w, ka_w};
    const int vo[15] = {O_LN1G, O_LN1B, O_QB, O_KB, O_VB, O_TB, O_PB, O_FFNG, O_FFNB, O_B1, O_B2, O_QAB, O_KAB, O_QAW, O_KAW};
    const int vn[15] = {256, 256, 256, 256, 256, 256, 256, 256, 256, 256, 256, 8, 8, 2048, 2048};
    for (int i = 0; i < 15; ++i) { tab.p[i] = vp[i]; tab.off[i] = vo[i]; tab.n[i] = vn[i]; }
    convert_vecs_k<<<15, 256, 0, stream>>>(tab, flag, sv);

    dim3 tb(32, 8);
    // 2) weight transposes (K x N -> N x K), converting dtype
    const void* wsrc[7] = {q_w, k_w, v_w, p_w, t_w, w1, w2};
    u16b* wdst[7] = {qT, kT, vT, pT, tT, w1T, w2T};
    for (int i = 0; i < 7; ++i)
        transpose_in_k<<<dim3(8, 8, 1), tb, 0, stream>>>(wsrc[i], wdst[i], 256, 256, flag);
    // 3) x (n, 256, 1600) -> xT (n, 1600, 256), converting dtype
    transpose_in_k<<<dim3(50, 8, 32), tb, 0, stream>>>(x, xT, 256, 1600, flag);
    // 4) ln_x (51328 rows; pad rows = ln1_b)
    rowln_k<<<12832, 256, 0, stream>>>(xT, sv + O_LN1G, sv + O_LN1B, sv + O_LN1B, B1, 51200, 51328);
    // 5-7) q_full / k_full / v_full
    gemm256<0><<<dim3(401, 2), 256, 0, stream>>>(B1, qT, sv + O_QB, nullptr, B2);
    gemm256<0><<<dim3(401, 2), 256, 0, stream>>>(B1, kT, sv + O_KB, nullptr, B3);
    gemm256<0><<<dim3(401, 2), 256, 0, stream>>>(B1, vT, sv + O_VB, nullptr, B4);
    // 8) fused q-pool/k-pool/window-means: qbar -> B1, vbarP -> vbb
    pool_fused<<<2048, 512, 0, stream>>>(B2, B3, B4, sv, B1, vbb);
    // 9) att = qbar @ p_w + p_b + x_residual
    gemm256<2><<<dim3(400, 2), 256, 0, stream>>>(B1, pT, sv + O_PB, xT, att);
    // 10) tmp = vbarP @ t_w + t_b   (into B2)
    gemm256<0><<<dim3(400, 2), 256, 0, stream>>>(vbb, tT, sv + O_TB, nullptr, B2);
    // 11) att += tmp @ p_w          (in place)
    gemm256<2><<<dim3(400, 2), 256, 0, stream>>>(B2, pT, nullptr, att, att);
    // 12) fn = LN(att) with ffn params (into B4)
    rowln_k<<<12800, 256, 0, stream>>>(att, sv + O_FFNG, sv + O_FFNB, nullptr, B4, 51200, 51200);
    // 13) h1 = gelu(fn @ w1 + b1) (into B1)
    gemm256<3><<<dim3(400, 2), 256, 0, stream>>>(B4, w1T, sv + O_B1, nullptr, B1);
    // 14) y = h1 @ w2 + b2 + att (in place into att)
    gemm256<2><<<dim3(400, 2), 256, 0, stream>>>(B1, w2T, sv + O_B2, att, att);
    // 15) y (n, 1600, 256) -> out (n, 256, 1600), converting dtype
    transpose_out_k<<<dim3(8, 50, 32), tb, 0, stream>>>(att, d_out, 1600, 256, flag);
}

// Round 5
// 466.761 us; speedup vs baseline: 1.7000x; 1.2360x over previous
//
#include <hip/hip_runtime.h>
#include <hip/hip_bf16.h>

typedef unsigned short u16b;                                   // raw bf16 bits
typedef __attribute__((ext_vector_type(8))) short short8;      // 8 bf16 = 4 VGPR (MFMA A/B frag)
typedef __attribute__((ext_vector_type(4))) float floatx4;     // MFMA C/D frag

#define DEV static __device__ __forceinline__

DEV float sh2f(unsigned short s) { union { unsigned u; float f; } c; c.u = ((unsigned)s) << 16; return c.f; }
DEV unsigned short f2b(float f) {
    unsigned u = __float_as_uint(f);
    u += 0x7FFF + ((u >> 16) & 1);      // RNE to bf16
    return (unsigned short)(u >> 16);
}

// packed small-vector offsets (elements) — shared host/device
constexpr int O_LN1G = 0, O_LN1B = 256, O_QB = 512, O_KB = 768, O_VB = 1024,
              O_TB = 1280, O_PB = 1536, O_FFNG = 1792, O_FFNB = 2048,
              O_B1 = 2304, O_B2 = 2560, O_QAB = 2816, O_KAB = 2824,
              O_QAW = 2832, O_KAW = 4880;

// ---------------------------------------------------------------------------
// Input dtype sniffer. flag[0] = 1 -> inputs are fp32;  0 -> bf16.
// ---------------------------------------------------------------------------
__global__ void detect_k(const unsigned* __restrict__ xw, int* __restrict__ flag) {
    __shared__ int cnt;
    if (threadIdx.x == 0) cnt = 0;
    __syncthreads();
    int my = 0;
    for (int i = threadIdx.x; i < 4096; i += 256) {
        unsigned w = xw[i];
        unsigned e0 = (w >> 7) & 0xFFu;      // low half's bf16 exponent
        if (e0 >= 0xC0u) my++;
    }
    atomicAdd(&cnt, my);
    __syncthreads();
    if (threadIdx.x == 0) flag[0] = (cnt > 64) ? 1 : 0;
}

DEV unsigned short load_cvt(const void* src, size_t idx, int fp32) {
    return fp32 ? f2b(((const float*)src)[idx]) : ((const u16b*)src)[idx];
}

// ---------------------------------------------------------------------------
// Pack + convert the small vectors (gains/biases/qa/ka) into sv (bf16).
// ---------------------------------------------------------------------------
struct VecTab { const void* p[15]; int off[15]; int n[15]; };

__global__ __launch_bounds__(256)
void convert_vecs_k(VecTab tab, const int* __restrict__ flag, u16b* __restrict__ sv) {
    int e = blockIdx.x, fp32 = flag[0];
    const void* s = tab.p[e];
    int n = tab.n[e], off = tab.off[e];
    for (int i = threadIdx.x; i < n; i += 256)
        sv[off + i] = load_cvt(s, i, fp32);
}

// ---------------------------------------------------------------------------
// Batched 256x256 weight transpose (7 weights in one launch, grid.z = idx)
// ---------------------------------------------------------------------------
struct WSrcTab { const void* p[7]; };

__global__ void wtrans_k(WSrcTab tab, u16b* __restrict__ wT, const int* __restrict__ flag) {
    __shared__ u16b tile[32][33];
    int fp32 = flag[0];
    const void* src = tab.p[blockIdx.z];
    u16b* dst = wT + (size_t)blockIdx.z * 65536;
    int c0 = blockIdx.x * 32, r0 = blockIdx.y * 32;
    int tx = threadIdx.x, ty = threadIdx.y;
#pragma unroll
    for (int i = 0; i < 32; i += 8)
        tile[ty + i][tx] = load_cvt(src, (size_t)(r0 + ty + i) * 256 + c0 + tx, fp32);
    __syncthreads();
#pragma unroll
    for (int i = 0; i < 32; i += 8)
        dst[(size_t)(c0 + ty + i) * 256 + r0 + tx] = tile[tx][ty + i];
}

// ---------------------------------------------------------------------------
// dtype-converting per-z 2D transpose (x input), and converting output transpose
// ---------------------------------------------------------------------------
__global__ void transpose_in_k(const void* __restrict__ src, u16b* __restrict__ dst,
                               int rows, int cols, const int* __restrict__ flag) {
    __shared__ u16b tile[32][33];
    int fp32 = flag[0];
    int c0 = blockIdx.x * 32, r0 = blockIdx.y * 32;
    size_t zb = (size_t)blockIdx.z * rows * cols;
    int tx = threadIdx.x, ty = threadIdx.y;
#pragma unroll
    for (int i = 0; i < 32; i += 8)
        tile[ty + i][tx] = load_cvt(src, zb + (size_t)(r0 + ty + i) * cols + c0 + tx, fp32);
    __syncthreads();
#pragma unroll
    for (int i = 0; i < 32; i += 8)
        dst[zb + (size_t)(c0 + ty + i) * rows + r0 + tx] = tile[tx][ty + i];
}

__global__ void transpose_out_k(const u16b* __restrict__ src, void* __restrict__ dst,
                                int rows, int cols, const int* __restrict__ flag) {
    __shared__ u16b tile[32][33];
    int fp32 = flag[0];
    int c0 = blockIdx.x * 32, r0 = blockIdx.y * 32;
    size_t zb = (size_t)blockIdx.z * rows * cols;
    int tx = threadIdx.x, ty = threadIdx.y;
#pragma unroll
    for (int i = 0; i < 32; i += 8)
        tile[ty + i][tx] = src[zb + (size_t)(r0 + ty + i) * cols + c0 + tx];
    __syncthreads();
#pragma unroll
    for (int i = 0; i < 32; i += 8) {
        size_t idx = zb + (size_t)(c0 + ty + i) * rows + r0 + tx;
        unsigned short v = tile[tx][ty + i];
        if (fp32) ((float*)dst)[idx] = sh2f(v);
        else      ((u16b*)dst)[idx] = v;
    }
}

// ---------------------------------------------------------------------------
// Row LayerNorm over C=256. One wave per row, 4 rows per block.
// ---------------------------------------------------------------------------
__global__ __launch_bounds__(256)
void rowln_k(const u16b* __restrict__ src, const u16b* __restrict__ g,
             const u16b* __restrict__ be, const u16b* __restrict__ padrow,
             u16b* __restrict__ dst, int valid, int total) {
    int wv = threadIdx.x >> 6, lane = threadIdx.x & 63;
    int r = blockIdx.x * 4 + wv;
    if (r >= total) return;
    int c = lane * 4;
    if (r >= valid) {
        *(ushort4*)&dst[(size_t)r * 256 + c] = *(const ushort4*)&padrow[c];
        return;
    }
    ushort4 raw = *(const ushort4*)&src[(size_t)r * 256 + c];
    float x0 = sh2f(raw.x), x1 = sh2f(raw.y), x2 = sh2f(raw.z), x3 = sh2f(raw.w);
    float s  = x0 + x1 + x2 + x3;
    float sq = x0 * x0 + x1 * x1 + x2 * x2 + x3 * x3;
#pragma unroll
    for (int o = 32; o; o >>= 1) { s += __shfl_xor(s, o); sq += __shfl_xor(sq, o); }
    float mean = s * (1.f / 256.f);
    float var  = sq * (1.f / 256.f) - mean * mean;
    float rs   = rsqrtf(var + 1e-5f);
    ushort4 o;
    o.x = f2b((x0 - mean) * rs * sh2f(g[c + 0]) + sh2f(be[c + 0]));
    o.y = f2b((x1 - mean) * rs * sh2f(g[c + 1]) + sh2f(be[c + 1]));
    o.z = f2b((x2 - mean) * rs * sh2f(g[c + 2]) + sh2f(be[c + 2]));
    o.w = f2b((x3 - mean) * rs * sh2f(g[c + 3]) + sh2f(be[c + 3]));
    *(ushort4*)&dst[(size_t)r * 256 + c] = o;
}

// ---------------------------------------------------------------------------
// bf16 GEMM: out[M x N] = A[M x 256] @ W (Wt is N x K = W^T) + epilogue
// EPI: 0 = +bias; 2 = +bias +addm; 3 = gelu(acc+bias);
//      4 = +bias, tri-split output: out[(col>>8)*triStride + row*256 + (col&255)]
// ---------------------------------------------------------------------------
template <int EPI>
__global__ __launch_bounds__(256)
void gemm256(const u16b* __restrict__ A, const u16b* __restrict__ Wt,
             const u16b* __restrict__ bias, const u16b* __restrict__ addm,
             u16b* __restrict__ out, size_t triStride) {
    __shared__ u16b As[128 * 72];
    __shared__ u16b Bs[128 * 72];
    const int tid = threadIdx.x;
    const int m0 = blockIdx.x * 128, n0 = blockIdx.y * 128;
    const int wv = tid >> 6, lane = tid & 63;
    const int wrow = (wv >> 1) * 64, wcol = (wv & 1) * 64;
    const int fr = lane & 15;            // frag row (m for A, n for B), also C col
    const int fq = lane >> 4;            // quad: k offset fq*8; C row offset fq*4
    floatx4 acc[4][4];
    const floatx4 zero = {0.f, 0.f, 0.f, 0.f};
#pragma unroll
    for (int i = 0; i < 4; ++i)
#pragma unroll
        for (int j = 0; j < 4; ++j) acc[i][j] = zero;

    for (int kt = 0; kt < 256; kt += 64) {
#pragma unroll
        for (int kk = 0; kk < 4; ++kk) {
            int chunk = tid + kk * 256;              // 1024 chunks of 8 elems
            int row = chunk >> 3, col = (chunk & 7) * 8;
            *(uint4*)&As[row * 72 + col] = *(const uint4*)&A[(size_t)(m0 + row) * 256 + kt + col];
            *(uint4*)&Bs[row * 72 + col] = *(const uint4*)&Wt[(size_t)(n0 + row) * 256 + kt + col];
        }
        __syncthreads();
#pragma unroll
        for (int s = 0; s < 2; ++s) {
            short8 af[4], bfr[4];
#pragma unroll
            for (int i = 0; i < 4; ++i)
                af[i] = *(short8*)&As[(wrow + i * 16 + fr) * 72 + s * 32 + fq * 8];
#pragma unroll
            for (int j = 0; j < 4; ++j)
                bfr[j] = *(short8*)&Bs[(wcol + j * 16 + fr) * 72 + s * 32 + fq * 8];
#pragma unroll
            for (int i = 0; i < 4; ++i)
#pragma unroll
                for (int j = 0; j < 4; ++j)
                    acc[i][j] = __builtin_amdgcn_mfma_f32_16x16x32_bf16(af[i], bfr[j], acc[i][j], 0, 0, 0);
        }
        __syncthreads();
    }
    // epilogue; C/D layout: col = lane&15, row = (lane>>4)*4 + reg
    float bv[4];
#pragma unroll
    for (int j = 0; j < 4; ++j) bv[j] = bias ? sh2f(bias[n0 + wcol + j * 16 + fr]) : 0.f;
#pragma unroll
    for (int i = 0; i < 4; ++i) {
#pragma unroll
        for (int r = 0; r < 4; ++r) {
            int row = m0 + wrow + i * 16 + fq * 4 + r;
            size_t ro = (size_t)row * 256;
#pragma unroll
            for (int j = 0; j < 4; ++j) {
                int col = n0 + wcol + j * 16 + fr;
                float val = acc[i][j][r] + bv[j];
                if (EPI == 2) val += sh2f(addm[ro + col]);
                if (EPI == 3) val = 0.5f * val * (1.0f + erff(val * 0.70710678118654752f));
                if (EPI == 4) out[(size_t)(col >> 8) * triStride + ro + (col & 255)] = f2b(val);
                else          out[ro + col] = f2b(val);
            }
        }
    }
}

// ---------------------------------------------------------------------------
// One softmax-pool stage (q or k). Logits via MFMA; pooled value via
// vectorized short8 gathers with a 16-slot LDS reduction.
// ---------------------------------------------------------------------------
DEV void pool_stage(const u16b* __restrict__ S, const u16b* __restrict__ sv,
                    int awoff, int aboff, const float* mult, float* outPool,
                    const int* srow, u16b* su, float* slog, float* spool, int tid) {
    // build su rows 0..7 : su[h*260 + c] = aw[c,h] (* mult[c]); rows 8..15 stay 0
    for (int i = tid; i < 2048; i += 512) {
        int c = i >> 3, h = i & 7;
        float w = sh2f(sv[awoff + i]);
        if (mult) w *= mult[c];
        su[h * 260 + c] = f2b(w);
    }
    __syncthreads();
    int wv = tid >> 6, lane = tid & 63;
    int fr = lane & 15, fq = lane >> 4;
    floatx4 acc = {0.f, 0.f, 0.f, 0.f};
    const u16b* Ar = S + (size_t)srow[wv * 16 + fr] * 256;
#pragma unroll
    for (int s = 0; s < 8; ++s) {
        short8 a  = *(const short8*)&Ar[s * 32 + fq * 8];
        short8 bb = *(const short8*)&su[fr * 260 + s * 32 + fq * 8];
        acc = __builtin_amdgcn_mfma_f32_16x16x32_bf16(a, bb, acc, 0, 0, 0);
    }
    float abv = sh2f(sv[aboff + (fr & 7)]);
    if (fr < 8) {
#pragma unroll
        for (int r = 0; r < 4; ++r)
            slog[(wv * 16 + fq * 4 + r) * 9 + fr] = (acc[r] + abv) * 0.17677669529663687f;
    }
    __syncthreads();
    // softmax over l=0..124 for head h = wv (8 waves, 8 heads)
    {
        int h = wv;
        float v0 = (lane < 125) ? slog[lane * 9 + h] : -1e30f;
        float v1 = (lane + 64 < 125) ? slog[(lane + 64) * 9 + h] : -1e30f;
        float mx = fmaxf(v0, v1);
#pragma unroll
        for (int o = 32; o; o >>= 1) mx = fmaxf(mx, __shfl_xor(mx, o));
        float e0 = (lane < 125) ? __expf(v0 - mx) : 0.f;
        float e1 = (lane + 64 < 125) ? __expf(v1 - mx) : 0.f;
        float s = e0 + e1;
#pragma unroll
        for (int o = 32; o; o >>= 1) s += __shfl_xor(s, o);
        float inv = 1.f / s;
        if (lane < 125) slog[lane * 9 + h] = e0 * inv;
        if (lane + 64 < 125) slog[(lane + 64) * 9 + h] = e1 * inv;
    }
    __syncthreads();
    // pooled value: thread = (l-slot ls of 16, channel-group c8 of 8); short8 loads
    int c8 = (tid & 31) * 8, ls = tid >> 5;
    int h2 = c8 >> 5;
    float a8[8] = {0.f, 0.f, 0.f, 0.f, 0.f, 0.f, 0.f, 0.f};
    for (int l = ls; l < 125; l += 16) {
        float w = slog[l * 9 + h2];
        short8 d8 = *(const short8*)&S[(size_t)srow[l] * 256 + c8];
#pragma unroll
        for (int j = 0; j < 8; ++j) a8[j] += w * sh2f((unsigned short)d8[j]);
    }
#pragma unroll
    for (int j = 0; j < 8; ++j) spool[ls * 256 + c8 + j] = a8[j];
    __syncthreads();
    if (tid < 256) {
        float s = 0.f;
#pragma unroll
        for (int q = 0; q < 16; ++q) s += spool[q * 256 + tid];
        outPool[tid] = s;
    }
    __syncthreads();
}

// ---------------------------------------------------------------------------
// Fused q-pool, k-pool, window-means. One block per b=(n,t), 512 threads.
// XCD swizzle keeps same-n blocks on one XCD for L2 gather reuse.
// ---------------------------------------------------------------------------
__global__ __launch_bounds__(512)
void pool_fused(const u16b* __restrict__ qf, const u16b* __restrict__ kf,
                const u16b* __restrict__ vf, const u16b* __restrict__ sv,
                u16b* __restrict__ qbar, u16b* __restrict__ vbarP) {
    __shared__ int srow[128];
    __shared__ u16b su[16 * 260];
    __shared__ float slog[128 * 9];
    __shared__ float spool[16 * 256];
    __shared__ float spq[256], spk[256];
    int bid = blockIdx.x;
    int b = ((bid & 7) << 8) | (bid >> 3);   // XCD-aware: bid%8 -> n-group
    int n = b >> 6, t = b & 63;
    int tid = threadIdx.x;
    if (tid < 128) {
        int l = tid < 125 ? tid : 124;       // clamp; rows >=125 never used downstream
        int w = l / 25, v = l - w * 25, tt = t + w - 2;
        srow[tid] = ((unsigned)tt < 64u) ? (n * 64 + tt) * 25 + v : 51200;
    }
    for (int i = tid; i < 8 * 260; i += 512) su[8 * 260 + i] = 0;
    __syncthreads();
    // q-pool -> spq (stays in LDS)
    pool_stage(qf, sv, O_QAW, O_QAB, nullptr, spq, srow, su, slog, spool, tid);
    // qbar = mean_w q  (short8 loads, 800 units of 8 channels)
    for (int i = tid; i < 800; i += 512) {
        int v = i >> 5, c8 = (i & 31) * 8;
        float s[8] = {0.f, 0.f, 0.f, 0.f, 0.f, 0.f, 0.f, 0.f};
#pragma unroll
        for (int w = 0; w < 5; ++w) {
            short8 d8 = *(const short8*)&qf[(size_t)srow[w * 25 + v] * 256 + c8];
#pragma unroll
            for (int j = 0; j < 8; ++j) s[j] += sh2f((unsigned short)d8[j]);
        }
        unsigned short o[8];
#pragma unroll
        for (int j = 0; j < 8; ++j) o[j] = f2b(s[j] * 0.2f);
        *(uint4*)&qbar[((size_t)b * 25 + v) * 256 + c8] = *(uint4*)o;
    }
    // k-pool with pq modulation -> spk
    pool_stage(kf, sv, O_KAW, O_KAB, spq, spk, srow, su, slog, spool, tid);
    // vbarP = mean_w v * pk
    for (int i = tid; i < 800; i += 512) {
        int v = i >> 5, c8 = (i & 31) * 8;
        float s[8] = {0.f, 0.f, 0.f, 0.f, 0.f, 0.f, 0.f, 0.f};
#pragma unroll
        for (int w = 0; w < 5; ++w) {
            short8 d8 = *(const short8*)&vf[(size_t)srow[w * 25 + v] * 256 + c8];
#pragma unroll
            for (int j = 0; j < 8; ++j) s[j] += sh2f((unsigned short)d8[j]);
        }
        unsigned short o[8];
#pragma unroll
        for (int j = 0; j < 8; ++j) o[j] = f2b(s[j] * 0.2f * spk[c8 + j]);
        *(uint4*)&vbarP[((size_t)b * 25 + v) * 256 + c8] = *(uint4*)o;
    }
}

// ---------------------------------------------------------------------------
extern "C" void kernel_launch(void* const* d_in, const int* in_sizes, int n_in,
                              void* d_out, int out_size, void* d_ws, size_t ws_size,
                              hipStream_t stream) {
    (void)in_sizes; (void)n_in; (void)out_size; (void)ws_size;
    const void* x    = d_in[0];
    const void* ln1g = d_in[1];  const void* ln1b = d_in[2];
    const void* q_w  = d_in[3];  const void* q_b  = d_in[4];
    const void* qa_w = d_in[5];  const void* qa_b = d_in[6];
    const void* k_w  = d_in[7];  const void* k_b  = d_in[8];
    const void* ka_w = d_in[9];  const void* ka_b = d_in[10];
    const void* v_w  = d_in[11]; const void* v_b  = d_in[12];
    const void* t_w  = d_in[13]; const void* t_b  = d_in[14];
    const void* p_w  = d_in[15]; const void* p_b  = d_in[16];
    const void* ffng = d_in[17]; const void* ffnb = d_in[18];
    const void* w1   = d_in[19]; const void* b1   = d_in[20];
    const void* w2   = d_in[21]; const void* b2   = d_in[22];

    char* ws = (char*)d_ws;
    size_t off = 0;
    auto alloc = [&](size_t bytes) { void* p = ws + off; off += (bytes + 255) & ~(size_t)255; return p; };
    const size_t RPAD = 51328;           // 51200 valid rows + 128 pad rows
    int*   flag = (int*)alloc(256);
    u16b*  sv  = (u16b*)alloc(8192 * 2);                // packed small vectors
    u16b*  wT  = (u16b*)alloc((size_t)7 * 65536 * 2);   // qT kT vT pT tT w1T w2T
    u16b*  xT  = (u16b*)alloc((size_t)51200 * 256 * 2);
    u16b*  B1  = (u16b*)alloc(RPAD * 256 * 2);          // ln_x -> qbar -> h1
    u16b*  B2  = (u16b*)alloc(RPAD * 256 * 2);          // q_full -> tmp2   (tri base)
    u16b*  B3  = (u16b*)alloc(RPAD * 256 * 2);          // k_full
    u16b*  B4  = (u16b*)alloc(RPAD * 256 * 2);          // v_full -> fn
    u16b*  att = (u16b*)alloc((size_t)51200 * 256 * 2); // att, then y in place
    u16b*  vbb = (u16b*)alloc((size_t)51200 * 256 * 2); // vbarP

    u16b* qT  = wT + 0 * 65536; u16b* pT  = wT + 3 * 65536;
    u16b* tT  = wT + 4 * 65536; u16b* w1T = wT + 5 * 65536;
    u16b* w2T = wT + 6 * 65536;

    // 0) dtype detection
    detect_k<<<1, 256, 0, stream>>>((const unsigned*)x, flag);
    // 1) small-vector conversion
    VecTab tab;
    const void* vp[15] = {ln1g, ln1b, q_b, k_b, v_b, t_b, p_b, ffng, ffnb, b1, b2, qa_b, ka_b, qa_w, ka_w};
    const int vo[15] = {O_LN1G, O_LN1B, O_QB, O_KB, O_VB, O_TB, O_PB, O_FFNG, O_FFNB, O_B1, O_B2, O_QAB, O_KAB, O_QAW, O_KAW};
    const int vn[15] = {256, 256, 256, 256, 256, 256, 256, 256, 256, 256, 256, 8, 8, 2048, 2048};
    for (int i = 0; i < 15; ++i) { tab.p[i] = vp[i]; tab.off[i] = vo[i]; tab.n[i] = vn[i]; }
    convert_vecs_k<<<15, 256, 0, stream>>>(tab, flag, sv);

    dim3 tb(32, 8);
    // 2) batched weight transposes (q,k,v first three -> contiguous N=768 block)
    WSrcTab wt;
    wt.p[0] = q_w; wt.p[1] = k_w; wt.p[2] = v_w; wt.p[3] = p_w; wt.p[4] = t_w;
    wt.p[5] = w1;  wt.p[6] = w2;
    wtrans_k<<<dim3(8, 8, 7), tb, 0, stream>>>(wt, wT, flag);
    // 3) x (n, 256, 1600) -> xT (n, 1600, 256), converting dtype
    transpose_in_k<<<dim3(50, 8, 32), tb, 0, stream>>>(x, xT, 256, 1600, flag);
    // 4) ln_x (51328 rows; pad rows = ln1_b)
    rowln_k<<<12832, 256, 0, stream>>>(xT, sv + O_LN1G, sv + O_LN1B, sv + O_LN1B, B1, 51200, 51328);
    // 5) fused q/k/v GEMM: N=768 (weights contiguous), tri-split out B2/B3/B4
    gemm256<4><<<dim3(401, 6), 256, 0, stream>>>(B1, qT, sv + O_QB, nullptr, B2, RPAD * 256);
    // 6) fused q-pool/k-pool/window-means: qbar -> B1, vbarP -> vbb
    pool_fused<<<2048, 512, 0, stream>>>(B2, B3, B4, sv, B1, vbb);
    // 7) tmp2 = vbarP @ t_w + t_b + qbar   (into B2)
    gemm256<2><<<dim3(400, 2), 256, 0, stream>>>(vbb, tT, sv + O_TB, B1, B2, 0);
    // 8) att = tmp2 @ p_w + p_b + x_residual
    gemm256<2><<<dim3(400, 2), 256, 0, stream>>>(B2, pT, sv + O_PB, xT, att, 0);
    // 9) fn = LN(att) with ffn params (into B4)
    rowln_k<<<12800, 256, 0, stream>>>(att, sv + O_FFNG, sv + O_FFNB, nullptr, B4, 51200, 51200);
    // 10) h1 = gelu(fn @ w1 + b1) (into B1)
    gemm256<3><<<dim3(400, 2), 256, 0, stream>>>(B4, w1T, sv + O_B1, nullptr, B1, 0);
    // 11) y = h1 @ w2 + b2 + att (in place into att)
    gemm256<2><<<dim3(400, 2), 256, 0, stream>>>(B1, w2T, sv + O_B2, att, att, 0);
    // 12) y (n, 1600, 256) -> out (n, 256, 1600), converting dtype
    transpose_out_k<<<dim3(8, 50, 32), tb, 0, stream>>>(att, d_out, 1600, 256, flag);
}

// Round 6
// 429.488 us; speedup vs baseline: 1.8475x; 1.0868x over previous
//
#include <hip/hip_runtime.h>
#include <hip/hip_bf16.h>

typedef unsigned short u16b;                                   // raw bf16 bits
typedef __attribute__((ext_vector_type(8))) short short8;      // 8 bf16 = 4 VGPR (MFMA A/B frag)
typedef __attribute__((ext_vector_type(4))) float floatx4;     // MFMA C/D frag

#define DEV static __device__ __forceinline__

DEV float sh2f(unsigned short s) { union { unsigned u; float f; } c; c.u = ((unsigned)s) << 16; return c.f; }
DEV unsigned short f2b(float f) {
    unsigned u = __float_as_uint(f);
    u += 0x7FFF + ((u >> 16) & 1);      // RNE to bf16
    return (unsigned short)(u >> 16);
}

// packed small-vector offsets (elements) — shared host/device
constexpr int O_LN1G = 0, O_LN1B = 256, O_QB = 512, O_KB = 768, O_VB = 1024,
              O_TB = 1280, O_PB = 1536, O_FFNG = 1792, O_FFNB = 2048,
              O_B1 = 2304, O_B2 = 2560, O_QAB = 2816, O_KAB = 2824,
              O_QAW = 2832, O_KAW = 4880, O_CV = 6928;

// ---------------------------------------------------------------------------
// Input dtype sniffer. flag[0] = 1 -> inputs are fp32;  0 -> bf16.
// ---------------------------------------------------------------------------
__global__ void detect_k(const unsigned* __restrict__ xw, int* __restrict__ flag) {
    __shared__ int cnt;
    if (threadIdx.x == 0) cnt = 0;
    __syncthreads();
    int my = 0;
    for (int i = threadIdx.x; i < 4096; i += 256) {
        unsigned w = xw[i];
        unsigned e0 = (w >> 7) & 0xFFu;      // low half's bf16 exponent
        if (e0 >= 0xC0u) my++;
    }
    atomicAdd(&cnt, my);
    __syncthreads();
    if (threadIdx.x == 0) flag[0] = (cnt > 64) ? 1 : 0;
}

DEV unsigned short load_cvt(const void* src, size_t idx, int fp32) {
    return fp32 ? f2b(((const float*)src)[idx]) : ((const u16b*)src)[idx];
}

// ---------------------------------------------------------------------------
// Pack + convert the small vectors (gains/biases/qa/ka) into sv (bf16).
// ---------------------------------------------------------------------------
struct VecTab { const void* p[15]; int off[15]; int n[15]; };

__global__ __launch_bounds__(256)
void convert_vecs_k(VecTab tab, const int* __restrict__ flag, u16b* __restrict__ sv) {
    int e = blockIdx.x, fp32 = flag[0];
    const void* s = tab.p[e];
    int n = tab.n[e], off = tab.off[e];
    for (int i = threadIdx.x; i < n; i += 256)
        sv[off + i] = load_cvt(s, i, fp32);
}

// ---------------------------------------------------------------------------
// Batched 256x256 weight transpose: 8 slices, per-slice dst offset + row stride.
// dst[c * rstride + r] = src[r, c]
// ---------------------------------------------------------------------------
struct W8 { const void* p[8]; unsigned dstoff[8]; unsigned rstride[8]; };

__global__ void wtrans_k(W8 tab, u16b* __restrict__ base, const int* __restrict__ flag) {
    __shared__ u16b tile[32][33];
    int fp32 = flag[0];
    const void* src = tab.p[blockIdx.z];
    u16b* dst = base + tab.dstoff[blockIdx.z];
    unsigned rs = tab.rstride[blockIdx.z];
    int c0 = blockIdx.x * 32, r0 = blockIdx.y * 32;
    int tx = threadIdx.x, ty = threadIdx.y;
#pragma unroll
    for (int i = 0; i < 32; i += 8)
        tile[ty + i][tx] = load_cvt(src, (size_t)(r0 + ty + i) * 256 + c0 + tx, fp32);
    __syncthreads();
#pragma unroll
    for (int i = 0; i < 32; i += 8)
        dst[(size_t)(c0 + ty + i) * rs + r0 + tx] = tile[tx][ty + i];
}

// ---------------------------------------------------------------------------
// dtype-converting x transpose in, y transpose out
// ---------------------------------------------------------------------------
__global__ void transpose_in_k(const void* __restrict__ src, u16b* __restrict__ dst,
                               int rows, int cols, const int* __restrict__ flag) {
    __shared__ u16b tile[32][33];
    int fp32 = flag[0];
    int c0 = blockIdx.x * 32, r0 = blockIdx.y * 32;
    size_t zb = (size_t)blockIdx.z * rows * cols;
    int tx = threadIdx.x, ty = threadIdx.y;
#pragma unroll
    for (int i = 0; i < 32; i += 8)
        tile[ty + i][tx] = load_cvt(src, zb + (size_t)(r0 + ty + i) * cols + c0 + tx, fp32);
    __syncthreads();
#pragma unroll
    for (int i = 0; i < 32; i += 8)
        dst[zb + (size_t)(c0 + ty + i) * rows + r0 + tx] = tile[tx][ty + i];
}

__global__ void transpose_out_k(const u16b* __restrict__ src, void* __restrict__ dst,
                                int rows, int cols, const int* __restrict__ flag) {
    __shared__ u16b tile[32][33];
    int fp32 = flag[0];
    int c0 = blockIdx.x * 32, r0 = blockIdx.y * 32;
    size_t zb = (size_t)blockIdx.z * rows * cols;
    int tx = threadIdx.x, ty = threadIdx.y;
#pragma unroll
    for (int i = 0; i < 32; i += 8)
        tile[ty + i][tx] = src[zb + (size_t)(r0 + ty + i) * cols + c0 + tx];
    __syncthreads();
#pragma unroll
    for (int i = 0; i < 32; i += 8) {
        size_t idx = zb + (size_t)(c0 + ty + i) * rows + r0 + tx;
        unsigned short v = tile[tx][ty + i];
        if (fp32) ((float*)dst)[idx] = sh2f(v);
        else      ((u16b*)dst)[idx] = v;
    }
}

// ---------------------------------------------------------------------------
// Per-row LN stats (mean, rstd) over C=256. One wave per row, 4 rows/block.
// Rows >= valid get (0,0): downstream inline-LN then yields the bias vector.
// ---------------------------------------------------------------------------
__global__ __launch_bounds__(256)
void rowstats_k(const u16b* __restrict__ src, float2* __restrict__ st,
                int valid, int total) {
    int wv = threadIdx.x >> 6, lane = threadIdx.x & 63;
    int r = blockIdx.x * 4 + wv;
    if (r >= total) return;
    if (r >= valid) { if (lane == 0) st[r] = make_float2(0.f, 0.f); return; }
    int c = lane * 4;
    ushort4 raw = *(const ushort4*)&src[(size_t)r * 256 + c];
    float x0 = sh2f(raw.x), x1 = sh2f(raw.y), x2 = sh2f(raw.z), x3 = sh2f(raw.w);
    float s  = x0 + x1 + x2 + x3;
    float sq = x0 * x0 + x1 * x1 + x2 * x2 + x3 * x3;
#pragma unroll
    for (int o = 32; o; o >>= 1) { s += __shfl_xor(s, o); sq += __shfl_xor(sq, o); }
    float mean = s * (1.f / 256.f);
    float var  = sq * (1.f / 256.f) - mean * mean;
    if (lane == 0) st[r] = make_float2(mean, rsqrtf(var + 1e-5f));
}

// ---------------------------------------------------------------------------
// cvec[j] = t_b @ p_w[:, j] + p_b[j]  via pT rows (contiguous dot). 1 block.
// ---------------------------------------------------------------------------
__global__ __launch_bounds__(256)
void cvec_k(const u16b* __restrict__ pT, u16b* __restrict__ sv) {
    int j = threadIdx.x;
    float acc = sh2f(sv[O_PB + j]);
    const u16b* row = pT + (size_t)j * 256;
    for (int i = 0; i < 256; i += 8) {
        short8 t8 = *(const short8*)&sv[O_TB + i];
        short8 p8 = *(const short8*)&row[i];
#pragma unroll
        for (int u = 0; u < 8; ++u)
            acc += sh2f((unsigned short)t8[u]) * sh2f((unsigned short)p8[u]);
    }
    sv[O_CV + j] = f2b(acc);
}

// ---------------------------------------------------------------------------
// bf16 GEMM: out[M x N] = A[M x K] @ W (Wt is N x K) + epilogue.
// LNA=1: apply LayerNorm (stats + gvec/bvec) to A rows during LDS staging (K==256).
// EPI: 0 = +bias (out stride osParam); 2 = +bias +addm (stride 256);
//      3 = gelu(acc+bias); 4 = +bias tri-split: out[(col>>8)*osParam + row*256 + (col&255)]
// ---------------------------------------------------------------------------
template <int EPI, int LNA>
__global__ __launch_bounds__(256)
void gemm256(const u16b* __restrict__ A, int aStride, int K,
             const u16b* __restrict__ Wt,
             const u16b* __restrict__ bias, const u16b* __restrict__ addm,
             u16b* __restrict__ out, size_t osParam,
             const float2* __restrict__ stats,
             const u16b* __restrict__ gvec, const u16b* __restrict__ bvec) {
    __shared__ u16b As[128 * 72];
    __shared__ u16b Bs[128 * 72];
    __shared__ float sg[256], sb[256];
    const int tid = threadIdx.x;
    const int m0 = blockIdx.x * 128, n0 = blockIdx.y * 128;
    const int wv = tid >> 6, lane = tid & 63;
    const int wrow = (wv >> 1) * 64, wcol = (wv & 1) * 64;
    const int fr = lane & 15;            // frag row (m for A, n for B), also C col
    const int fq = lane >> 4;            // quad: k offset fq*8; C row offset fq*4
    floatx4 acc[4][4];
    const floatx4 zero = {0.f, 0.f, 0.f, 0.f};
#pragma unroll
    for (int i = 0; i < 4; ++i)
#pragma unroll
        for (int j = 0; j < 4; ++j) acc[i][j] = zero;

    float2 strow[4];
    if (LNA) {
        sg[tid] = sh2f(gvec[tid]);
        sb[tid] = sh2f(bvec[tid]);
#pragma unroll
        for (int kk = 0; kk < 4; ++kk) strow[kk] = stats[m0 + (tid >> 3) + kk * 32];
        __syncthreads();
    }

    for (int kt = 0; kt < K; kt += 64) {
#pragma unroll
        for (int kk = 0; kk < 4; ++kk) {
            int chunk = tid + kk * 256;              // 1024 chunks of 8 elems
            int row = chunk >> 3, col = (chunk & 7) * 8;
            union { uint4 u; unsigned short h[8]; } rw;
            rw.u = *(const uint4*)&A[(size_t)(m0 + row) * aStride + kt + col];
            if (LNA) {
#pragma unroll
                for (int j = 0; j < 8; ++j) {
                    float f = sh2f(rw.h[j]);
                    f = (f - strow[kk].x) * strow[kk].y * sg[kt + col + j] + sb[kt + col + j];
                    rw.h[j] = f2b(f);
                }
            }
            *(uint4*)&As[row * 72 + col] = rw.u;
            *(uint4*)&Bs[row * 72 + col] = *(const uint4*)&Wt[(size_t)(n0 + row) * K + kt + col];
        }
        __syncthreads();
#pragma unroll
        for (int s = 0; s < 2; ++s) {
            short8 af[4], bfr[4];
#pragma unroll
            for (int i = 0; i < 4; ++i)
                af[i] = *(short8*)&As[(wrow + i * 16 + fr) * 72 + s * 32 + fq * 8];
#pragma unroll
            for (int j = 0; j < 4; ++j)
                bfr[j] = *(short8*)&Bs[(wcol + j * 16 + fr) * 72 + s * 32 + fq * 8];
#pragma unroll
            for (int i = 0; i < 4; ++i)
#pragma unroll
                for (int j = 0; j < 4; ++j)
                    acc[i][j] = __builtin_amdgcn_mfma_f32_16x16x32_bf16(af[i], bfr[j], acc[i][j], 0, 0, 0);
        }
        __syncthreads();
    }
    // epilogue; C/D layout: col = lane&15, row = (lane>>4)*4 + reg
    float bv[4];
#pragma unroll
    for (int j = 0; j < 4; ++j) bv[j] = bias ? sh2f(bias[n0 + wcol + j * 16 + fr]) : 0.f;
#pragma unroll
    for (int i = 0; i < 4; ++i) {
#pragma unroll
        for (int r = 0; r < 4; ++r) {
            int row = m0 + wrow + i * 16 + fq * 4 + r;
            size_t ro = (size_t)row * 256;
#pragma unroll
            for (int j = 0; j < 4; ++j) {
                int col = n0 + wcol + j * 16 + fr;
                float val = acc[i][j][r] + bv[j];
                if (EPI == 2) val += sh2f(addm[ro + col]);
                if (EPI == 3) val = 0.5f * val * (1.0f + erff(val * 0.70710678118654752f));
                if (EPI == 4)      out[(size_t)(col >> 8) * osParam + ro + (col & 255)] = f2b(val);
                else if (EPI == 0) out[(size_t)row * osParam + col] = f2b(val);
                else               out[ro + col] = f2b(val);
            }
        }
    }
}

// ---------------------------------------------------------------------------
// One softmax-pool stage (q or k). Logits via MFMA; pooled value via
// vectorized short8 gathers; l-slot in low lane bits for coalesced lines.
// ---------------------------------------------------------------------------
DEV void pool_stage(const u16b* __restrict__ S, const u16b* __restrict__ sv,
                    int awoff, int aboff, const float* mult, float* outPool,
                    const int* srow, u16b* su, float* slog, float* spool, int tid) {
    // build su rows 0..7 : su[h*260 + c] = aw[c,h] (* mult[c]); rows 8..15 stay 0
    for (int i = tid; i < 2048; i += 512) {
        int c = i >> 3, h = i & 7;
        float w = sh2f(sv[awoff + i]);
        if (mult) w *= mult[c];
        su[h * 260 + c] = f2b(w);
    }
    __syncthreads();
    int wv = tid >> 6, lane = tid & 63;
    int fr = lane & 15, fq = lane >> 4;
    floatx4 acc = {0.f, 0.f, 0.f, 0.f};
    const u16b* Ar = S + (size_t)srow[wv * 16 + fr] * 256;
#pragma unroll
    for (int s = 0; s < 8; ++s) {
        short8 a  = *(const short8*)&Ar[s * 32 + fq * 8];
        short8 bb = *(const short8*)&su[fr * 260 + s * 32 + fq * 8];
        acc = __builtin_amdgcn_mfma_f32_16x16x32_bf16(a, bb, acc, 0, 0, 0);
    }
    float abv = sh2f(sv[aboff + (fr & 7)]);
    if (fr < 8) {
#pragma unroll
        for (int r = 0; r < 4; ++r)
            slog[(wv * 16 + fq * 4 + r) * 9 + fr] = (acc[r] + abv) * 0.17677669529663687f;
    }
    __syncthreads();
    // softmax over l=0..124 for head h = wv (8 waves, 8 heads)
    {
        int h = wv;
        float v0 = (lane < 125) ? slog[lane * 9 + h] : -1e30f;
        float v1 = (lane + 64 < 125) ? slog[(lane + 64) * 9 + h] : -1e30f;
        float mx = fmaxf(v0, v1);
#pragma unroll
        for (int o = 32; o; o >>= 1) mx = fmaxf(mx, __shfl_xor(mx, o));
        float e0 = (lane < 125) ? __expf(v0 - mx) : 0.f;
        float e1 = (lane + 64 < 125) ? __expf(v1 - mx) : 0.f;
        float s = e0 + e1;
#pragma unroll
        for (int o = 32; o; o >>= 1) s += __shfl_xor(s, o);
        float inv = 1.f / s;
        if (lane < 125) slog[lane * 9 + h] = e0 * inv;
        if (lane + 64 < 125) slog[(lane + 64) * 9 + h] = e1 * inv;
    }
    __syncthreads();
    // pooled value: ls in LOW bits (rows of one line gathered by 4 lanes)
    int ls = tid & 15, cg = tid >> 4;       // cg 0..31
    int c8 = cg * 8, h2 = c8 >> 5;
    float a8[8] = {0.f, 0.f, 0.f, 0.f, 0.f, 0.f, 0.f, 0.f};
    for (int l = ls; l < 125; l += 16) {
        float w = slog[l * 9 + h2];
        short8 d8 = *(const short8*)&S[(size_t)srow[l] * 256 + c8];
#pragma unroll
        for (int j = 0; j < 8; ++j) a8[j] += w * sh2f((unsigned short)d8[j]);
    }
#pragma unroll
    for (int j = 0; j < 8; ++j) spool[ls * 260 + c8 + j] = a8[j];
    __syncthreads();
    if (tid < 256) {
        float s = 0.f;
#pragma unroll
        for (int q = 0; q < 16; ++q) s += spool[q * 260 + tid];
        outPool[tid] = s;
    }
    __syncthreads();
}

// ---------------------------------------------------------------------------
// Fused q-pool, k-pool, window-means. One block per b=(n,t), 512 threads.
// Writes combo rows CB[(b*25+v)*512 + {0..255 = vbarP, 256..511 = qbar}].
// ---------------------------------------------------------------------------
__global__ __launch_bounds__(512)
void pool_fused(const u16b* __restrict__ qf, const u16b* __restrict__ kf,
                const u16b* __restrict__ vf, const u16b* __restrict__ sv,
                u16b* __restrict__ CB) {
    __shared__ int srow[128];
    __shared__ u16b su[16 * 260];
    __shared__ float slog[128 * 9];
    __shared__ float spool[16 * 260];
    __shared__ float spq[256], spk[256];
    int bid = blockIdx.x;
    int b = ((bid & 7) << 8) | (bid >> 3);   // XCD-aware: bid%8 -> n-group
    int n = b >> 6, t = b & 63;
    int tid = threadIdx.x;
    if (tid < 128) {
        int l = tid < 125 ? tid : 124;
        int w = l / 25, v = l - w * 25, tt = t + w - 2;
        srow[tid] = ((unsigned)tt < 64u) ? (n * 64 + tt) * 25 + v : 51200;
    }
    for (int i = tid; i < 8 * 260; i += 512) su[8 * 260 + i] = 0;
    __syncthreads();
    // q-pool -> spq (stays in LDS)
    pool_stage(qf, sv, O_QAW, O_QAB, nullptr, spq, srow, su, slog, spool, tid);
    // qbar = mean_w q  -> CB cols 256..511
    for (int i = tid; i < 800; i += 512) {
        int v = i >> 5, c8 = (i & 31) * 8;
        float s[8] = {0.f, 0.f, 0.f, 0.f, 0.f, 0.f, 0.f, 0.f};
#pragma unroll
        for (int w = 0; w < 5; ++w) {
            short8 d8 = *(const short8*)&qf[(size_t)srow[w * 25 + v] * 256 + c8];
#pragma unroll
            for (int j = 0; j < 8; ++j) s[j] += sh2f((unsigned short)d8[j]);
        }
        unsigned short o[8];
#pragma unroll
        for (int j = 0; j < 8; ++j) o[j] = f2b(s[j] * 0.2f);
        *(uint4*)&CB[((size_t)b * 25 + v) * 512 + 256 + c8] = *(uint4*)o;
    }
    // k-pool with pq modulation -> spk
    pool_stage(kf, sv, O_KAW, O_KAB, spq, spk, srow, su, slog, spool, tid);
    // vbarP = mean_w v * pk -> CB cols 0..255
    for (int i = tid; i < 800; i += 512) {
        int v = i >> 5, c8 = (i & 31) * 8;
        float s[8] = {0.f, 0.f, 0.f, 0.f, 0.f, 0.f, 0.f, 0.f};
#pragma unroll
        for (int w = 0; w < 5; ++w) {
            short8 d8 = *(const short8*)&vf[(size_t)srow[w * 25 + v] * 256 + c8];
#pragma unroll
            for (int j = 0; j < 8; ++j) s[j] += sh2f((unsigned short)d8[j]);
        }
        unsigned short o[8];
#pragma unroll
        for (int j = 0; j < 8; ++j) o[j] = f2b(s[j] * 0.2f * spk[c8 + j]);
        *(uint4*)&CB[((size_t)b * 25 + v) * 512 + c8] = *(uint4*)o;
    }
}

// ---------------------------------------------------------------------------
extern "C" void kernel_launch(void* const* d_in, const int* in_sizes, int n_in,
                              void* d_out, int out_size, void* d_ws, size_t ws_size,
                              hipStream_t stream) {
    (void)in_sizes; (void)n_in; (void)out_size; (void)ws_size;
    const void* x    = d_in[0];
    const void* ln1g = d_in[1];  const void* ln1b = d_in[2];
    const void* q_w  = d_in[3];  const void* q_b  = d_in[4];
    const void* qa_w = d_in[5];  const void* qa_b = d_in[6];
    const void* k_w  = d_in[7];  const void* k_b  = d_in[8];
    const void* ka_w = d_in[9];  const void* ka_b = d_in[10];
    const void* v_w  = d_in[11]; const void* v_b  = d_in[12];
    const void* t_w  = d_in[13]; const void* t_b  = d_in[14];
    const void* p_w  = d_in[15]; const void* p_b  = d_in[16];
    const void* ffng = d_in[17]; const void* ffnb = d_in[18];
    const void* w1   = d_in[19]; const void* b1   = d_in[20];
    const void* w2   = d_in[21]; const void* b2   = d_in[22];

    char* ws = (char*)d_ws;
    size_t off = 0;
    auto alloc = [&](size_t bytes) { void* p = ws + off; off += (bytes + 255) & ~(size_t)255; return p; };
    const size_t RPAD = 51328;           // 51200 valid rows + 128 pad rows
    int*    flag = (int*)alloc(256);
    u16b*   sv   = (u16b*)alloc(8192 * 2);                // packed small vectors
    u16b*   wT   = (u16b*)alloc((size_t)7 * 65536 * 2);   // qT kT vT pT tT w1T w2T
    u16b*   cW   = (u16b*)alloc((size_t)256 * 512 * 2);   // comboWt: [TP^T | p_w^T]
    u16b*   xT   = (u16b*)alloc(RPAD * 256 * 2);
    u16b*   Bq   = (u16b*)alloc(RPAD * 256 * 2);          // q_full -> h1
    u16b*   Bk   = (u16b*)alloc(RPAD * 256 * 2);
    u16b*   Bv   = (u16b*)alloc(RPAD * 256 * 2);
    u16b*   CB   = (u16b*)alloc((size_t)51200 * 512 * 2); // [vbarP | qbar]
    u16b*   att  = (u16b*)alloc((size_t)51200 * 256 * 2); // att, then y in place
    float2* st1  = (float2*)alloc(RPAD * 8);
    float2* st2  = (float2*)alloc((size_t)51200 * 8);

    u16b* pT  = wT + 3 * 65536;
    u16b* tT  = wT + 4 * 65536;
    u16b* w1T = wT + 5 * 65536;
    u16b* w2T = wT + 6 * 65536;

    // 0) dtype detection
    detect_k<<<1, 256, 0, stream>>>((const unsigned*)x, flag);
    // 1) small-vector conversion
    VecTab tab;
    const void* vp[15] = {ln1g, ln1b, q_b, k_b, v_b, t_b, p_b, ffng, ffnb, b1, b2, qa_b, ka_b, qa_w, ka_w};
    const int vo[15] = {O_LN1G, O_LN1B, O_QB, O_KB, O_VB, O_TB, O_PB, O_FFNG, O_FFNB, O_B1, O_B2, O_QAB, O_KAB, O_QAW, O_KAW};
    const int vn[15] = {256, 256, 256, 256, 256, 256, 256, 256, 256, 256, 256, 8, 8, 2048, 2048};
    for (int i = 0; i < 15; ++i) { tab.p[i] = vp[i]; tab.off[i] = vo[i]; tab.n[i] = vn[i]; }
    convert_vecs_k<<<15, 256, 0, stream>>>(tab, flag, sv);

    dim3 tb(32, 8);
    // 2) weight transposes: slices 0-6 -> wT slabs; slice 7: p_w^T -> cW cols 256.. (stride 512)
    W8 wt;
    const void* wsrc[8] = {q_w, k_w, v_w, p_w, t_w, w1, w2, p_w};
    for (int i = 0; i < 8; ++i) {
        wt.p[i] = wsrc[i];
        wt.dstoff[i] = (i < 7) ? (unsigned)(i * 65536) : (unsigned)((cW + 256) - wT);
        wt.rstride[i] = (i < 7) ? 256u : 512u;
    }
    wtrans_k<<<dim3(8, 8, 8), tb, 0, stream>>>(wt, wT, flag);
    // 3) cvec = t_b @ p_w + p_b  (into sv+O_CV)
    cvec_k<<<1, 256, 0, stream>>>(pT, sv);
    // 4) TP^T into cW cols 0..255:  out[m,k] = sum_j pT[m,j] tT[k,j] = (t_w@p_w)[k,m]
    gemm256<0, 0><<<dim3(2, 2), 256, 0, stream>>>(pT, 256, 256, tT, nullptr, nullptr,
                                                  cW, 512, nullptr, nullptr, nullptr);
    // 5) x (n, 256, 1600) -> xT (n, 1600, 256)
    transpose_in_k<<<dim3(50, 8, 32), tb, 0, stream>>>(x, xT, 256, 1600, flag);
    // 6) LN stats of xT rows (pad rows -> (0,0) => inline LN yields ln1_b)
    rowstats_k<<<12832, 256, 0, stream>>>(xT, st1, 51200, 51328);
    // 7) fused q/k/v GEMM with inline LN; tri-split out Bq/Bk/Bv
    gemm256<4, 1><<<dim3(401, 6), 256, 0, stream>>>(xT, 256, 256, wT, sv + O_QB, nullptr,
                                                    Bq, RPAD * 256, st1, sv + O_LN1G, sv + O_LN1B);
    // 8) fused pools + window means -> CB
    pool_fused<<<2048, 512, 0, stream>>>(Bq, Bk, Bv, sv, CB);
    // 9) att = CB @ comboWt^T + cvec + x_residual   (K=512)
    gemm256<2, 0><<<dim3(400, 2), 256, 0, stream>>>(CB, 512, 512, cW, sv + O_CV, xT,
                                                    att, 256, nullptr, nullptr, nullptr);
    // 10) LN stats of att rows
    rowstats_k<<<12800, 256, 0, stream>>>(att, st2, 51200, 51200);
    // 11) h1 = gelu(LN(att) @ w1 + b1) with inline LN (into Bq)
    gemm256<3, 1><<<dim3(400, 2), 256, 0, stream>>>(att, 256, 256, w1T, sv + O_B1, nullptr,
                                                    Bq, 256, st2, sv + O_FFNG, sv + O_FFNB);
    // 12) y = h1 @ w2 + b2 + att (in place into att)
    gemm256<2, 0><<<dim3(400, 2), 256, 0, stream>>>(Bq, 256, 256, w2T, sv + O_B2, att,
                                                    att, 256, nullptr, nullptr, nullptr);
    // 13) y (n, 1600, 256) -> out (n, 256, 1600)
    transpose_out_k<<<dim3(8, 50, 32), tb, 0, stream>>>(att, d_out, 1600, 256, flag);
}

// Round 7
// 417.139 us; speedup vs baseline: 1.9022x; 1.0296x over previous
//
#include <hip/hip_runtime.h>
#include <hip/hip_bf16.h>

typedef unsigned short u16b;                                   // raw bf16 bits
typedef __attribute__((ext_vector_type(8))) short short8;      // 8 bf16 = 4 VGPR (MFMA A/B frag)
typedef __attribute__((ext_vector_type(4))) float floatx4;     // MFMA C/D frag

#define DEV static __device__ __forceinline__

DEV float sh2f(unsigned short s) { union { unsigned u; float f; } c; c.u = ((unsigned)s) << 16; return c.f; }
DEV unsigned short f2b(float f) {
    unsigned u = __float_as_uint(f);
    u += 0x7FFF + ((u >> 16) & 1);      // RNE to bf16
    return (unsigned short)(u >> 16);
}

// packed small-vector offsets (elements) — shared host/device
constexpr int O_LN1G = 0, O_LN1B = 256, O_QB = 512, O_KB = 768, O_VB = 1024,
              O_TB = 1280, O_PB = 1536, O_FFNG = 1792, O_FFNB = 2048,
              O_B1 = 2304, O_B2 = 2560, O_QAB = 2816, O_KAB = 2824,
              O_QAW = 2832, O_KAW = 4880, O_CV = 6928;

// ---------------------------------------------------------------------------
// Input dtype sniffer. flag[0] = 1 -> inputs are fp32;  0 -> bf16.
// ---------------------------------------------------------------------------
__global__ void detect_k(const unsigned* __restrict__ xw, int* __restrict__ flag) {
    __shared__ int cnt;
    if (threadIdx.x == 0) cnt = 0;
    __syncthreads();
    int my = 0;
    for (int i = threadIdx.x; i < 4096; i += 256) {
        unsigned w = xw[i];
        unsigned e0 = (w >> 7) & 0xFFu;      // low half's bf16 exponent
        if (e0 >= 0xC0u) my++;
    }
    atomicAdd(&cnt, my);
    __syncthreads();
    if (threadIdx.x == 0) flag[0] = (cnt > 64) ? 1 : 0;
}

DEV unsigned short load_cvt(const void* src, size_t idx, int fp32) {
    return fp32 ? f2b(((const float*)src)[idx]) : ((const u16b*)src)[idx];
}

// ---------------------------------------------------------------------------
// Pack + convert the small vectors (gains/biases/qa/ka) into sv (bf16).
// ---------------------------------------------------------------------------
struct VecTab { const void* p[15]; int off[15]; int n[15]; };

__global__ __launch_bounds__(256)
void convert_vecs_k(VecTab tab, const int* __restrict__ flag, u16b* __restrict__ sv) {
    int e = blockIdx.x, fp32 = flag[0];
    const void* s = tab.p[e];
    int n = tab.n[e], off = tab.off[e];
    for (int i = threadIdx.x; i < n; i += 256)
        sv[off + i] = load_cvt(s, i, fp32);
}

// ---------------------------------------------------------------------------
// Batched 256x256 weight transpose: 8 slices, per-slice dst offset + row stride.
// dst[c * rstride + r] = src[r, c]
// ---------------------------------------------------------------------------
struct W8 { const void* p[8]; unsigned dstoff[8]; unsigned rstride[8]; };

__global__ void wtrans_k(W8 tab, u16b* __restrict__ base, const int* __restrict__ flag) {
    __shared__ u16b tile[32][33];
    int fp32 = flag[0];
    const void* src = tab.p[blockIdx.z];
    u16b* dst = base + tab.dstoff[blockIdx.z];
    unsigned rs = tab.rstride[blockIdx.z];
    int c0 = blockIdx.x * 32, r0 = blockIdx.y * 32;
    int tx = threadIdx.x, ty = threadIdx.y;
#pragma unroll
    for (int i = 0; i < 32; i += 8)
        tile[ty + i][tx] = load_cvt(src, (size_t)(r0 + ty + i) * 256 + c0 + tx, fp32);
    __syncthreads();
#pragma unroll
    for (int i = 0; i < 32; i += 8)
        dst[(size_t)(c0 + ty + i) * rs + r0 + tx] = tile[tx][ty + i];
}

// ---------------------------------------------------------------------------
// dtype-converting x transpose in, y transpose out
// ---------------------------------------------------------------------------
__global__ void transpose_in_k(const void* __restrict__ src, u16b* __restrict__ dst,
                               int rows, int cols, const int* __restrict__ flag) {
    __shared__ u16b tile[32][33];
    int fp32 = flag[0];
    int c0 = blockIdx.x * 32, r0 = blockIdx.y * 32;
    size_t zb = (size_t)blockIdx.z * rows * cols;
    int tx = threadIdx.x, ty = threadIdx.y;
#pragma unroll
    for (int i = 0; i < 32; i += 8)
        tile[ty + i][tx] = load_cvt(src, zb + (size_t)(r0 + ty + i) * cols + c0 + tx, fp32);
    __syncthreads();
#pragma unroll
    for (int i = 0; i < 32; i += 8)
        dst[zb + (size_t)(c0 + ty + i) * rows + r0 + tx] = tile[tx][ty + i];
}

__global__ void transpose_out_k(const u16b* __restrict__ src, void* __restrict__ dst,
                                int rows, int cols, const int* __restrict__ flag) {
    __shared__ u16b tile[32][33];
    int fp32 = flag[0];
    int c0 = blockIdx.x * 32, r0 = blockIdx.y * 32;
    size_t zb = (size_t)blockIdx.z * rows * cols;
    int tx = threadIdx.x, ty = threadIdx.y;
#pragma unroll
    for (int i = 0; i < 32; i += 8)
        tile[ty + i][tx] = src[zb + (size_t)(r0 + ty + i) * cols + c0 + tx];
    __syncthreads();
#pragma unroll
    for (int i = 0; i < 32; i += 8) {
        size_t idx = zb + (size_t)(c0 + ty + i) * rows + r0 + tx;
        unsigned short v = tile[tx][ty + i];
        if (fp32) ((float*)dst)[idx] = sh2f(v);
        else      ((u16b*)dst)[idx] = v;
    }
}

// ---------------------------------------------------------------------------
// Per-row LN stats (mean, rstd) over C=256. One wave per row, 4 rows/block.
// Rows >= valid get (0,0): downstream inline-LN then yields the bias vector.
// ---------------------------------------------------------------------------
__global__ __launch_bounds__(256)
void rowstats_k(const u16b* __restrict__ src, float2* __restrict__ st,
                int valid, int total) {
    int wv = threadIdx.x >> 6, lane = threadIdx.x & 63;
    int r = blockIdx.x * 4 + wv;
    if (r >= total) return;
    if (r >= valid) { if (lane == 0) st[r] = make_float2(0.f, 0.f); return; }
    int c = lane * 4;
    ushort4 raw = *(const ushort4*)&src[(size_t)r * 256 + c];
    float x0 = sh2f(raw.x), x1 = sh2f(raw.y), x2 = sh2f(raw.z), x3 = sh2f(raw.w);
    float s  = x0 + x1 + x2 + x3;
    float sq = x0 * x0 + x1 * x1 + x2 * x2 + x3 * x3;
#pragma unroll
    for (int o = 32; o; o >>= 1) { s += __shfl_xor(s, o); sq += __shfl_xor(sq, o); }
    float mean = s * (1.f / 256.f);
    float var  = sq * (1.f / 256.f) - mean * mean;
    if (lane == 0) st[r] = make_float2(mean, rsqrtf(var + 1e-5f));
}

// ---------------------------------------------------------------------------
// cvec[j] = t_b @ p_w[:, j] + p_b[j]  via pT rows (contiguous dot). 1 block.
// ---------------------------------------------------------------------------
__global__ __launch_bounds__(256)
void cvec_k(const u16b* __restrict__ pT, u16b* __restrict__ sv) {
    int j = threadIdx.x;
    float acc = sh2f(sv[O_PB + j]);
    const u16b* row = pT + (size_t)j * 256;
    for (int i = 0; i < 256; i += 8) {
        short8 t8 = *(const short8*)&sv[O_TB + i];
        short8 p8 = *(const short8*)&row[i];
#pragma unroll
        for (int u = 0; u < 8; ++u)
            acc += sh2f((unsigned short)t8[u]) * sh2f((unsigned short)p8[u]);
    }
    sv[O_CV + j] = f2b(acc);
}

// ---------------------------------------------------------------------------
// bf16 GEMM: out[M x N] = A[M x K] @ W (Wt is N x K) + epilogue.
// LNA=1: apply LayerNorm (stats + gvec/bvec) to A rows during LDS staging (K==256).
// EPI: 0 = +bias (out stride osParam); 2 = +bias +addm (stride 256);
//      3 = gelu(acc+bias); 4 = +bias tri-split: out[(col>>8)*osParam + row*256 + (col&255)]
// ---------------------------------------------------------------------------
template <int EPI, int LNA>
__global__ __launch_bounds__(256)
void gemm256(const u16b* __restrict__ A, int aStride, int K,
             const u16b* __restrict__ Wt,
             const u16b* __restrict__ bias, const u16b* __restrict__ addm,
             u16b* __restrict__ out, size_t osParam,
             const float2* __restrict__ stats,
             const u16b* __restrict__ gvec, const u16b* __restrict__ bvec) {
    __shared__ u16b As[128 * 72];
    __shared__ u16b Bs[128 * 72];
    __shared__ float sg[256], sb[256];
    const int tid = threadIdx.x;
    const int m0 = blockIdx.x * 128, n0 = blockIdx.y * 128;
    const int wv = tid >> 6, lane = tid & 63;
    const int wrow = (wv >> 1) * 64, wcol = (wv & 1) * 64;
    const int fr = lane & 15;            // frag row (m for A, n for B), also C col
    const int fq = lane >> 4;            // quad: k offset fq*8; C row offset fq*4
    floatx4 acc[4][4];
    const floatx4 zero = {0.f, 0.f, 0.f, 0.f};
#pragma unroll
    for (int i = 0; i < 4; ++i)
#pragma unroll
        for (int j = 0; j < 4; ++j) acc[i][j] = zero;

    float2 strow[4];
    if (LNA) {
        sg[tid] = sh2f(gvec[tid]);
        sb[tid] = sh2f(bvec[tid]);
#pragma unroll
        for (int kk = 0; kk < 4; ++kk) strow[kk] = stats[m0 + (tid >> 3) + kk * 32];
        __syncthreads();
    }

    for (int kt = 0; kt < K; kt += 64) {
#pragma unroll
        for (int kk = 0; kk < 4; ++kk) {
            int chunk = tid + kk * 256;              // 1024 chunks of 8 elems
            int row = chunk >> 3, col = (chunk & 7) * 8;
            union { uint4 u; unsigned short h[8]; } rw;
            rw.u = *(const uint4*)&A[(size_t)(m0 + row) * aStride + kt + col];
            if (LNA) {
#pragma unroll
                for (int j = 0; j < 8; ++j) {
                    float f = sh2f(rw.h[j]);
                    f = (f - strow[kk].x) * strow[kk].y * sg[kt + col + j] + sb[kt + col + j];
                    rw.h[j] = f2b(f);
                }
            }
            *(uint4*)&As[row * 72 + col] = rw.u;
            *(uint4*)&Bs[row * 72 + col] = *(const uint4*)&Wt[(size_t)(n0 + row) * K + kt + col];
        }
        __syncthreads();
#pragma unroll
        for (int s = 0; s < 2; ++s) {
            short8 af[4], bfr[4];
#pragma unroll
            for (int i = 0; i < 4; ++i)
                af[i] = *(short8*)&As[(wrow + i * 16 + fr) * 72 + s * 32 + fq * 8];
#pragma unroll
            for (int j = 0; j < 4; ++j)
                bfr[j] = *(short8*)&Bs[(wcol + j * 16 + fr) * 72 + s * 32 + fq * 8];
#pragma unroll
            for (int i = 0; i < 4; ++i)
#pragma unroll
                for (int j = 0; j < 4; ++j)
                    acc[i][j] = __builtin_amdgcn_mfma_f32_16x16x32_bf16(af[i], bfr[j], acc[i][j], 0, 0, 0);
        }
        __syncthreads();
    }
    // epilogue; C/D layout: col = lane&15, row = (lane>>4)*4 + reg
    float bv[4];
#pragma unroll
    for (int j = 0; j < 4; ++j) bv[j] = bias ? sh2f(bias[n0 + wcol + j * 16 + fr]) : 0.f;
#pragma unroll
    for (int i = 0; i < 4; ++i) {
#pragma unroll
        for (int r = 0; r < 4; ++r) {
            int row = m0 + wrow + i * 16 + fq * 4 + r;
            size_t ro = (size_t)row * 256;
#pragma unroll
            for (int j = 0; j < 4; ++j) {
                int col = n0 + wcol + j * 16 + fr;
                float val = acc[i][j][r] + bv[j];
                if (EPI == 2) val += sh2f(addm[ro + col]);
                if (EPI == 3) val = 0.5f * val * (1.0f + erff(val * 0.70710678118654752f));
                if (EPI == 4)      out[(size_t)(col >> 8) * osParam + ro + (col & 255)] = f2b(val);
                else if (EPI == 0) out[(size_t)row * osParam + col] = f2b(val);
                else               out[ro + col] = f2b(val);
            }
        }
    }
}

// ---------------------------------------------------------------------------
// One softmax-pool stage (q or k). Logits via MFMA; pooled value via
// coalesced short8 gathers (32 lanes sweep one row's 256 channels).
// ---------------------------------------------------------------------------
DEV void pool_stage(const u16b* __restrict__ S, const u16b* __restrict__ sv,
                    int awoff, int aboff, const float* mult, float* outPool,
                    const int* srow, u16b* su, float* slog, float* spool, int tid) {
    // build su rows 0..7 : su[h*260 + c] = aw[c,h] (* mult[c]); rows 8..15 stay 0
    for (int i = tid; i < 2048; i += 512) {
        int c = i >> 3, h = i & 7;
        float w = sh2f(sv[awoff + i]);
        if (mult) w *= mult[c];
        su[h * 260 + c] = f2b(w);
    }
    __syncthreads();
    int wv = tid >> 6, lane = tid & 63;
    int fr = lane & 15, fq = lane >> 4;
    floatx4 acc = {0.f, 0.f, 0.f, 0.f};
    const u16b* Ar = S + (size_t)srow[wv * 16 + fr] * 256;
#pragma unroll
    for (int s = 0; s < 8; ++s) {
        short8 a  = *(const short8*)&Ar[s * 32 + fq * 8];
        short8 bb = *(const short8*)&su[fr * 260 + s * 32 + fq * 8];
        acc = __builtin_amdgcn_mfma_f32_16x16x32_bf16(a, bb, acc, 0, 0, 0);
    }
    float abv = sh2f(sv[aboff + (fr & 7)]);
    if (fr < 8) {
#pragma unroll
        for (int r = 0; r < 4; ++r)
            slog[(wv * 16 + fq * 4 + r) * 9 + fr] = (acc[r] + abv) * 0.17677669529663687f;
    }
    __syncthreads();
    // softmax over l=0..124 for head h = wv (8 waves, 8 heads)
    {
        int h = wv;
        float v0 = (lane < 125) ? slog[lane * 9 + h] : -1e30f;
        float v1 = (lane + 64 < 125) ? slog[(lane + 64) * 9 + h] : -1e30f;
        float mx = fmaxf(v0, v1);
#pragma unroll
        for (int o = 32; o; o >>= 1) mx = fmaxf(mx, __shfl_xor(mx, o));
        float e0 = (lane < 125) ? __expf(v0 - mx) : 0.f;
        float e1 = (lane + 64 < 125) ? __expf(v1 - mx) : 0.f;
        float s = e0 + e1;
#pragma unroll
        for (int o = 32; o; o >>= 1) s += __shfl_xor(s, o);
        float inv = 1.f / s;
        if (lane < 125) slog[lane * 9 + h] = e0 * inv;
        if (lane + 64 < 125) slog[(lane + 64) * 9 + h] = e1 * inv;
    }
    __syncthreads();
    // pooled value: c8 in LOW bits -> 32 lanes sweep a row (coalesced);
    // spool stride 260 floats to break power-of-2 bank aliasing.
    int c8 = (tid & 31) * 8, ls = tid >> 5;
    int h2 = c8 >> 5;
    float a8[8] = {0.f, 0.f, 0.f, 0.f, 0.f, 0.f, 0.f, 0.f};
    for (int l = ls; l < 125; l += 16) {
        float w = slog[l * 9 + h2];
        short8 d8 = *(const short8*)&S[(size_t)srow[l] * 256 + c8];
#pragma unroll
        for (int j = 0; j < 8; ++j) a8[j] += w * sh2f((unsigned short)d8[j]);
    }
#pragma unroll
    for (int j = 0; j < 8; ++j) spool[ls * 260 + c8 + j] = a8[j];
    __syncthreads();
    if (tid < 256) {
        float s = 0.f;
#pragma unroll
        for (int q = 0; q < 16; ++q) s += spool[q * 260 + tid];
        outPool[tid] = s;
    }
    __syncthreads();
}

// ---------------------------------------------------------------------------
// Fused q-pool, k-pool, window-means. One block per b=(n,t), 512 threads.
// Writes combo rows CB[(b*25+v)*512 + {0..255 = vbarP, 256..511 = qbar}].
// ---------------------------------------------------------------------------
__global__ __launch_bounds__(512)
void pool_fused(const u16b* __restrict__ qf, const u16b* __restrict__ kf,
                const u16b* __restrict__ vf, const u16b* __restrict__ sv,
                u16b* __restrict__ CB) {
    __shared__ int srow[128];
    __shared__ u16b su[16 * 260];
    __shared__ float slog[128 * 9];
    __shared__ float spool[16 * 260];
    __shared__ float spq[256], spk[256];
    int bid = blockIdx.x;
    int b = ((bid & 7) << 8) | (bid >> 3);   // XCD-aware: bid%8 -> n-group
    int n = b >> 6, t = b & 63;
    int tid = threadIdx.x;
    if (tid < 128) {
        int l = tid < 125 ? tid : 124;
        int w = l / 25, v = l - w * 25, tt = t + w - 2;
        srow[tid] = ((unsigned)tt < 64u) ? (n * 64 + tt) * 25 + v : 51200;
    }
    for (int i = tid; i < 8 * 260; i += 512) su[8 * 260 + i] = 0;
    __syncthreads();
    // q-pool -> spq (stays in LDS)
    pool_stage(qf, sv, O_QAW, O_QAB, nullptr, spq, srow, su, slog, spool, tid);
    // qbar = mean_w q  -> CB cols 256..511
    for (int i = tid; i < 800; i += 512) {
        int v = i >> 5, c8 = (i & 31) * 8;
        float s[8] = {0.f, 0.f, 0.f, 0.f, 0.f, 0.f, 0.f, 0.f};
#pragma unroll
        for (int w = 0; w < 5; ++w) {
            short8 d8 = *(const short8*)&qf[(size_t)srow[w * 25 + v] * 256 + c8];
#pragma unroll
            for (int j = 0; j < 8; ++j) s[j] += sh2f((unsigned short)d8[j]);
        }
        unsigned short o[8];
#pragma unroll
        for (int j = 0; j < 8; ++j) o[j] = f2b(s[j] * 0.2f);
        *(uint4*)&CB[((size_t)b * 25 + v) * 512 + 256 + c8] = *(uint4*)o;
    }
    // k-pool with pq modulation -> spk
    pool_stage(kf, sv, O_KAW, O_KAB, spq, spk, srow, su, slog, spool, tid);
    // vbarP = mean_w v * pk -> CB cols 0..255
    for (int i = tid; i < 800; i += 512) {
        int v = i >> 5, c8 = (i & 31) * 8;
        float s[8] = {0.f, 0.f, 0.f, 0.f, 0.f, 0.f, 0.f, 0.f};
#pragma unroll
        for (int w = 0; w < 5; ++w) {
            short8 d8 = *(const short8*)&vf[(size_t)srow[w * 25 + v] * 256 + c8];
#pragma unroll
            for (int j = 0; j < 8; ++j) s[j] += sh2f((unsigned short)d8[j]);
        }
        unsigned short o[8];
#pragma unroll
        for (int j = 0; j < 8; ++j) o[j] = f2b(s[j] * 0.2f * spk[c8 + j]);
        *(uint4*)&CB[((size_t)b * 25 + v) * 512 + c8] = *(uint4*)o;
    }
}

// ---------------------------------------------------------------------------
extern "C" void kernel_launch(void* const* d_in, const int* in_sizes, int n_in,
                              void* d_out, int out_size, void* d_ws, size_t ws_size,
                              hipStream_t stream) {
    (void)in_sizes; (void)n_in; (void)out_size; (void)ws_size;
    const void* x    = d_in[0];
    const void* ln1g = d_in[1];  const void* ln1b = d_in[2];
    const void* q_w  = d_in[3];  const void* q_b  = d_in[4];
    const void* qa_w = d_in[5];  const void* qa_b = d_in[6];
    const void* k_w  = d_in[7];  const void* k_b  = d_in[8];
    const void* ka_w = d_in[9];  const void* ka_b = d_in[10];
    const void* v_w  = d_in[11]; const void* v_b  = d_in[12];
    const void* t_w  = d_in[13]; const void* t_b  = d_in[14];
    const void* p_w  = d_in[15]; const void* p_b  = d_in[16];
    const void* ffng = d_in[17]; const void* ffnb = d_in[18];
    const void* w1   = d_in[19]; const void* b1   = d_in[20];
    const void* w2   = d_in[21]; const void* b2   = d_in[22];

    char* ws = (char*)d_ws;
    size_t off = 0;
    auto alloc = [&](size_t bytes) { void* p = ws + off; off += (bytes + 255) & ~(size_t)255; return p; };
    const size_t RPAD = 51328;           // 51200 valid rows + 128 pad rows
    int*    flag = (int*)alloc(256);
    u16b*   sv   = (u16b*)alloc(8192 * 2);                // packed small vectors
    u16b*   wT   = (u16b*)alloc((size_t)7 * 65536 * 2);   // qT kT vT pT tT w1T w2T
    u16b*   cW   = (u16b*)alloc((size_t)256 * 512 * 2);   // comboWt: [TP^T | p_w^T]
    u16b*   xT   = (u16b*)alloc(RPAD * 256 * 2);
    u16b*   Bq   = (u16b*)alloc(RPAD * 256 * 2);          // q_full -> h1
    u16b*   Bk   = (u16b*)alloc(RPAD * 256 * 2);
    u16b*   Bv   = (u16b*)alloc(RPAD * 256 * 2);
    u16b*   CB   = (u16b*)alloc((size_t)51200 * 512 * 2); // [vbarP | qbar]
    u16b*   att  = (u16b*)alloc((size_t)51200 * 256 * 2); // att, then y in place
    float2* st1  = (float2*)alloc(RPAD * 8);
    float2* st2  = (float2*)alloc((size_t)51200 * 8);

    u16b* pT  = wT + 3 * 65536;
    u16b* tT  = wT + 4 * 65536;
    u16b* w1T = wT + 5 * 65536;
    u16b* w2T = wT + 6 * 65536;

    // 0) dtype detection
    detect_k<<<1, 256, 0, stream>>>((const unsigned*)x, flag);
    // 1) small-vector conversion
    VecTab tab;
    const void* vp[15] = {ln1g, ln1b, q_b, k_b, v_b, t_b, p_b, ffng, ffnb, b1, b2, qa_b, ka_b, qa_w, ka_w};
    const int vo[15] = {O_LN1G, O_LN1B, O_QB, O_KB, O_VB, O_TB, O_PB, O_FFNG, O_FFNB, O_B1, O_B2, O_QAB, O_KAB, O_QAW, O_KAW};
    const int vn[15] = {256, 256, 256, 256, 256, 256, 256, 256, 256, 256, 256, 8, 8, 2048, 2048};
    for (int i = 0; i < 15; ++i) { tab.p[i] = vp[i]; tab.off[i] = vo[i]; tab.n[i] = vn[i]; }
    convert_vecs_k<<<15, 256, 0, stream>>>(tab, flag, sv);

    dim3 tb(32, 8);
    // 2) weight transposes: slices 0-6 -> wT slabs; slice 7: p_w^T -> cW cols 256.. (stride 512)
    W8 wt;
    const void* wsrc[8] = {q_w, k_w, v_w, p_w, t_w, w1, w2, p_w};
    for (int i = 0; i < 8; ++i) {
        wt.p[i] = wsrc[i];
        wt.dstoff[i] = (i < 7) ? (unsigned)(i * 65536) : (unsigned)((cW + 256) - wT);
        wt.rstride[i] = (i < 7) ? 256u : 512u;
    }
    wtrans_k<<<dim3(8, 8, 8), tb, 0, stream>>>(wt, wT, flag);
    // 3) cvec = t_b @ p_w + p_b  (into sv+O_CV)
    cvec_k<<<1, 256, 0, stream>>>(pT, sv);
    // 4) TP^T into cW cols 0..255:  out[m,k] = sum_j pT[m,j] tT[k,j] = (t_w@p_w)[k,m]
    gemm256<0, 0><<<dim3(2, 2), 256, 0, stream>>>(pT, 256, 256, tT, nullptr, nullptr,
                                                  cW, 512, nullptr, nullptr, nullptr);
    // 5) x (n, 256, 1600) -> xT (n, 1600, 256)
    transpose_in_k<<<dim3(50, 8, 32), tb, 0, stream>>>(x, xT, 256, 1600, flag);
    // 6) LN stats of xT rows (pad rows -> (0,0) => inline LN yields ln1_b)
    rowstats_k<<<12832, 256, 0, stream>>>(xT, st1, 51200, 51328);
    // 7) fused q/k/v GEMM with inline LN; tri-split out Bq/Bk/Bv
    gemm256<4, 1><<<dim3(401, 6), 256, 0, stream>>>(xT, 256, 256, wT, sv + O_QB, nullptr,
                                                    Bq, RPAD * 256, st1, sv + O_LN1G, sv + O_LN1B);
    // 8) fused pools + window means -> CB
    pool_fused<<<2048, 512, 0, stream>>>(Bq, Bk, Bv, sv, CB);
    // 9) att = CB @ comboWt^T + cvec + x_residual   (K=512)
    gemm256<2, 0><<<dim3(400, 2), 256, 0, stream>>>(CB, 512, 512, cW, sv + O_CV, xT,
                                                    att, 256, nullptr, nullptr, nullptr);
    // 10) LN stats of att rows
    rowstats_k<<<12800, 256, 0, stream>>>(att, st2, 51200, 51200);
    // 11) h1 = gelu(LN(att) @ w1 + b1) with inline LN (into Bq)
    gemm256<3, 1><<<dim3(400, 2), 256, 0, stream>>>(att, 256, 256, w1T, sv + O_B1, nullptr,
                                                    Bq, 256, st2, sv + O_FFNG, sv + O_FFNB);
    // 12) y = h1 @ w2 + b2 + att (in place into att)
    gemm256<2, 0><<<dim3(400, 2), 256, 0, stream>>>(Bq, 256, 256, w2T, sv + O_B2, att,
                                                    att, 256, nullptr, nullptr, nullptr);
    // 13) y (n, 1600, 256) -> out (n, 256, 1600)
    transpose_out_k<<<dim3(8, 50, 32), tb, 0, stream>>>(att, d_out, 1600, 256, flag);
}